// Round 6
// baseline (639.456 us; speedup 1.0000x reference)
//
#include <hip/hip_runtime.h>
#include <math.h>

typedef _Float16 f16x8 __attribute__((ext_vector_type(8)));
typedef float f32x4 __attribute__((ext_vector_type(4)));
typedef unsigned short ushort_t;

constexpr int HWp = 2304;
constexpr float EPS = 1e-5f;
constexpr int NTOK = 221184;   // 4 * 2304 * 24, pixel-major token order

// ws layout (bytes):
// 0 w1h 65536 | 65536 w1l | 131072 w2h | 196608 w2l
// 262144 qkBh 4096 | 266240 qkBl 4096 | 270336 qb2 64 | 270400 peG 3072
// 273664 xph (NTOK*128*2) | xpl (same size)
constexpr size_t XPH_OFF   = 273664;
constexpr size_t XP_ONE    = (size_t)NTOK * 128 * 2;
constexpr size_t XPL_OFF   = XPH_OFF + XP_ONE;
constexpr size_t WS_NEEDED = XPL_OFF + XP_ONE;

// swizzled ushort index, 256B rows (128 fp16 cols)
__device__ __forceinline__ int sidx(int row, int c) {
    return ((row << 8) + ((c << 1) ^ ((row & 7) << 4))) >> 1;
}
// swizzled ushort index, 128B rows (64 fp16 cols)
__device__ __forceinline__ int sidx2(int row, int c) {
    return ((row << 7) + ((c << 1) ^ ((row & 7) << 4))) >> 1;
}

// ---------------- prep: weights -> split fp16, fold Q+scale, PE table ----------------
__global__ void ltae_prep(const float* __restrict__ w_in0, const float* __restrict__ w_in1,
                          const float* __restrict__ Qm, const float* __restrict__ w_k,
                          const float* __restrict__ b_k, const int* __restrict__ bpos,
                          _Float16* __restrict__ w1h, _Float16* __restrict__ w1l,
                          _Float16* __restrict__ w2h, _Float16* __restrict__ w2l,
                          _Float16* __restrict__ qkBh, _Float16* __restrict__ qkBl,
                          float* __restrict__ qb2G, float* __restrict__ peG) {
    int i = blockIdx.x * 256 + threadIdx.x;
    if (i < 32768) {
        float v = w_in0[i];
        _Float16 h = (_Float16)v;
        w1h[i] = h; w1l[i] = (_Float16)(v - (float)h);
    } else if (i < 65536) {
        int j = i - 32768;
        float v = w_in1[j];
        _Float16 h = (_Float16)v;
        w2h[j] = h; w2l[j] = (_Float16)(v - (float)h);
    } else if (i < 67584) {
        int j = i - 65536; int h = j >> 7, k = j & 127;
        float s = 0.f;
        #pragma unroll
        for (int dk = 0; dk < 4; dk++) s = fmaf(Qm[h * 4 + dk], w_k[(h * 4 + dk) * 128 + k], s);
        s *= 0.5f;
        _Float16 hi = (_Float16)s;
        int ks = k >> 5, lg = (k >> 3) & 3, jj = k & 7;
        int pos = ((ks * 4 + lg) * 16 + h) * 8 + jj;
        qkBh[pos] = hi; qkBl[pos] = (_Float16)(s - (float)hi);
    } else if (i < 67600) {
        int h = i - 67584;
        float s = 0.f;
        #pragma unroll
        for (int dk = 0; dk < 4; dk++) s = fmaf(Qm[h * 4 + dk], b_k[h * 4 + dk], s);
        qb2G[h] = 0.5f * s;
    } else if (i < 68368) {
        int j = i - 67600;
        int bb = j / 192, r = j - bb * 192;
        int t = r >> 3, d = r & 7;
        const float dens[4] = {1.0f, 5.623413251903491f, 31.622776601683793f, 177.82794100389228f};
        float ang = (float)bpos[bb * 24 + t] / dens[d >> 1];
        peG[j] = (d & 1) ? cosf(ang) : sinf(ang);
    }
}

// ---------------- pack: x (B,T,C,H,W) -> token-major split fp16 arrays ----------------
__global__ __launch_bounds__(256) void ltae_pack(const float* __restrict__ x,
                                                 ushort_t* __restrict__ xph,
                                                 ushort_t* __restrict__ xpl) {
    __shared__ ushort_t th[64][136], tl[64][136];
    const int bid = blockIdx.x;              // 4b * 24t * 36 pixgroups = 3456
    const int pg = bid % 36;
    const int rem = bid / 36;
    const int t = rem % 24;
    const int b = rem / 24;
    const int pix0 = pg * 64;
    const float* src = x + ((size_t)((b * 24 + t) * 128)) * HWp + pix0;

    #pragma unroll
    for (int k = 0; k < 8; k++) {
        int i = threadIdx.x + (k << 8);      // 0..2047
        int c = i >> 4, p4 = (i & 15) << 2;
        float4 v = *(const float4*)(src + (size_t)c * HWp + p4);
        _Float16 h0 = (_Float16)v.x, h1 = (_Float16)v.y, h2 = (_Float16)v.z, h3 = (_Float16)v.w;
        th[p4 + 0][c] = __builtin_bit_cast(ushort_t, h0);
        tl[p4 + 0][c] = __builtin_bit_cast(ushort_t, (_Float16)(v.x - (float)h0));
        th[p4 + 1][c] = __builtin_bit_cast(ushort_t, h1);
        tl[p4 + 1][c] = __builtin_bit_cast(ushort_t, (_Float16)(v.y - (float)h1));
        th[p4 + 2][c] = __builtin_bit_cast(ushort_t, h2);
        tl[p4 + 2][c] = __builtin_bit_cast(ushort_t, (_Float16)(v.z - (float)h2));
        th[p4 + 3][c] = __builtin_bit_cast(ushort_t, h3);
        tl[p4 + 3][c] = __builtin_bit_cast(ushort_t, (_Float16)(v.w - (float)h3));
    }
    __syncthreads();
    #pragma unroll
    for (int k = 0; k < 2; k++) {
        int i = threadIdx.x + (k << 8);      // 0..511 = 64 px * 8 segs
        int px = i >> 3, seg = i & 7;
        int c0 = seg << 4;                   // 16 ushorts = 32B
        size_t tok = (size_t)(b * 2304 + pix0 + px) * 24 + t;
        uint4 vh0 = *(const uint4*)&th[px][c0];
        uint4 vh1 = *(const uint4*)&th[px][c0 + 8];
        uint4 vl0 = *(const uint4*)&tl[px][c0];
        uint4 vl1 = *(const uint4*)&tl[px][c0 + 8];
        *(uint4*)(xph + tok * 128 + c0)     = vh0;
        *(uint4*)(xph + tok * 128 + c0 + 8) = vh1;
        *(uint4*)(xpl + tok * 128 + c0)     = vl0;
        *(uint4*)(xpl + tok * 128 + c0 + 8) = vl1;
    }
}

// ---------------- main: 96 tokens (4 pixels) per 6-wave block ----------------
__global__ __launch_bounds__(384, 3) void ltae_main(
    const float* __restrict__ x,
    const ushort_t* __restrict__ xph, const ushort_t* __restrict__ xpl, const int packed,
    const float* __restrict__ b_in0, const float* __restrict__ g_in0, const float* __restrict__ be_in0,
    const float* __restrict__ b_in1, const float* __restrict__ g_in1, const float* __restrict__ be_in1,
    const float* __restrict__ g_innorm, const float* __restrict__ b_innorm,
    const float* __restrict__ w_m0, const float* __restrict__ b_m0,
    const float* __restrict__ g_m0, const float* __restrict__ be_m0,
    const float* __restrict__ w_m1, const float* __restrict__ b_m1,
    const float* __restrict__ g_m1, const float* __restrict__ be_m1,
    const float* __restrict__ g_out, const float* __restrict__ b_out,
    const _Float16* __restrict__ w1h, const _Float16* __restrict__ w1l,
    const _Float16* __restrict__ w2h, const _Float16* __restrict__ w2l,
    const _Float16* __restrict__ qkBh, const _Float16* __restrict__ qkBl,
    const float* __restrict__ qb2G, const float* __restrict__ peG,
    float* __restrict__ out)
{
    // weight/act region, 65536 B, unioned:
    //   per-quarter: W1h[0..8191] W1l[8192..] W2h[16384..] W2l[24576..]  (ushort idx)
    //   h1 quarter:  H1h = base (96*64=6144), H1l = +6144  (inside W1 region)
    //   xs2:         Xh = base (96*128=12288), Xl = +12288
    __shared__ __align__(16) ushort_t WB[32768];
    __shared__ float scP[4 * 16 * 24];     // scores, later ysP
    __shared__ float ovP[4 * 128];
    __shared__ float mmP[4 * 256];
    __shared__ float muS[4][16], rsS[4][16];
    __shared__ float peS[24][8];

    ushort_t* W1h = WB;
    ushort_t* W1l = WB + 8192;
    ushort_t* W2h = WB + 16384;
    ushort_t* W2l = WB + 24576;
    ushort_t* H1h = WB;
    ushort_t* H1l = WB + 6144;
    ushort_t* Xh  = WB;
    ushort_t* Xl  = WB + 12288;
    float* ysP = scP;

    const int tid = threadIdx.x;
    const int bid = blockIdx.x;
    const int sb  = (bid & 7) * 288 + (bid >> 3);   // bijective XCD swizzle (2304 = 8*288)
    const int b   = sb / 576;
    const int pixbase = (sb - b * 576) * 4;         // 4 consecutive pixels
    const int w  = tid >> 6;
    const int l  = tid & 63;
    const int lr = l & 15;
    const int lg = l >> 4;

    if (tid < 192) peS[tid >> 3][tid & 7] = peG[b * 192 + tid];

    // ---- A-fragments for this wave's 16 tokens (registers only) ----
    f16x8 Afh[4], Afl[4];
    const int tokbase = sb * 96 + w * 16;
    if (packed) {
        const ushort_t* ph = xph + (size_t)(tokbase + lr) * 128;
        const ushort_t* pl = xpl + (size_t)(tokbase + lr) * 128;
        #pragma unroll
        for (int ks = 0; ks < 4; ks++) {
            Afh[ks] = *(const f16x8*)(ph + ks * 32 + lg * 8);
            Afl[ks] = *(const f16x8*)(pl + ks * 32 + lg * 8);
        }
    } else {
        int tok = tokbase + lr;
        int bb = tok / 55296; int r1 = tok - bb * 55296;
        int pix = r1 / 24;    int t  = r1 - pix * 24;
        const float* xs = x + ((size_t)((bb * 24 + t) * 128)) * HWp + pix;
        #pragma unroll
        for (int ks = 0; ks < 4; ks++) {
            #pragma unroll
            for (int j = 0; j < 8; j++) {
                float v = xs[(size_t)(ks * 32 + lg * 8 + j) * HWp];
                _Float16 h = (_Float16)v;
                Afh[ks][j] = h;
                Afl[ks][j] = (_Float16)(v - (float)h);
            }
        }
    }

    // ---- quarter loop: GEMM1(64ch) + GN1 + GEMM2 partial-K ----
    f32x4 acc2[8];
    #pragma unroll
    for (int nt = 0; nt < 8; nt++) acc2[nt] = f32x4{0.f, 0.f, 0.f, 0.f};

    #pragma unroll 1
    for (int q = 0; q < 4; q++) {
        __syncthreads();   // previous quarter's LDS reads complete
        // cooperative weight staging: w1q 64x128, w2q 128x64 (hi/lo)
        for (int i = tid; i < 4096; i += 384) {
            int arr = i >> 10, rem = i & 1023;
            if (arr < 2) {
                int n = rem >> 4, kc = (rem & 15) << 3;
                const _Float16* src = (arr == 0 ? w1h : w1l) + (q * 64 + n) * 128 + kc;
                ushort_t* dst = (arr == 0 ? W1h : W1l);
                *(f16x8*)&dst[sidx(n, kc)] = *(const f16x8*)src;
            } else {
                int n = rem >> 3, kc = (rem & 7) << 3;
                const _Float16* src = (arr == 2 ? w2h : w2l) + n * 256 + q * 64 + kc;
                ushort_t* dst = (arr == 2 ? W2h : W2l);
                *(f16x8*)&dst[sidx2(n, kc)] = *(const f16x8*)src;
            }
        }
        __syncthreads();

        // GEMM1: wave's 16 tokens x quarter's 64 channels
        f32x4 acc1[4];
        #pragma unroll
        for (int nt = 0; nt < 4; nt++) acc1[nt] = f32x4{0.f, 0.f, 0.f, 0.f};
        #pragma unroll
        for (int ks = 0; ks < 4; ks++) {
            #pragma unroll
            for (int nt = 0; nt < 4; nt++) {
                f16x8 bh = *(const f16x8*)&W1h[sidx(nt * 16 + lr, ks * 32 + lg * 8)];
                f16x8 bl = *(const f16x8*)&W1l[sidx(nt * 16 + lr, ks * 32 + lg * 8)];
                acc1[nt] = __builtin_amdgcn_mfma_f32_16x16x32_f16(Afh[ks], bl, acc1[nt], 0, 0, 0);
                acc1[nt] = __builtin_amdgcn_mfma_f32_16x16x32_f16(Afl[ks], bh, acc1[nt], 0, 0, 0);
                acc1[nt] = __builtin_amdgcn_mfma_f32_16x16x32_f16(Afh[ks], bh, acc1[nt], 0, 0, 0);
            }
        }
        float bi1[4], gg1[4], bb1[4];
        #pragma unroll
        for (int nt = 0; nt < 4; nt++) {
            int n = q * 64 + nt * 16 + lr;
            bi1[nt] = b_in0[n]; gg1[nt] = g_in0[n]; bb1[nt] = be_in0[n];
        }
        __syncthreads();   // all W1 reads done; region becomes h1q

        // GN1 (wave-local, group == quarter) + ReLU -> H1q
        #pragma unroll
        for (int r = 0; r < 4; r++) {
            float v[4], s = 0.f, s2 = 0.f;
            #pragma unroll
            for (int nt = 0; nt < 4; nt++) {
                v[nt] = acc1[nt][r] + bi1[nt]; s += v[nt]; s2 += v[nt] * v[nt];
            }
            #pragma unroll
            for (int mk = 1; mk <= 8; mk <<= 1) { s += __shfl_xor(s, mk); s2 += __shfl_xor(s2, mk); }
            float mu = s * (1.f / 64.f);
            float rs = rsqrtf(s2 * (1.f / 64.f) - mu * mu + EPS);
            int row = w * 16 + lg * 4 + r;
            #pragma unroll
            for (int nt = 0; nt < 4; nt++) {
                float hv = fmaxf(fmaf((v[nt] - mu) * rs, gg1[nt], bb1[nt]), 0.f);
                _Float16 h16 = (_Float16)hv;
                int ii = sidx2(row, nt * 16 + lr);
                H1h[ii] = __builtin_bit_cast(ushort_t, h16);
                H1l[ii] = __builtin_bit_cast(ushort_t, (_Float16)(hv - (float)h16));
            }
        }
        __syncthreads();

        // GEMM2 partial: wave's 16 tokens x 128 out, K-slice = quarter
        f16x8 a2h[2], a2l[2];
        #pragma unroll
        for (int ks = 0; ks < 2; ks++) {
            a2h[ks] = *(const f16x8*)&H1h[sidx2(w * 16 + lr, ks * 32 + lg * 8)];
            a2l[ks] = *(const f16x8*)&H1l[sidx2(w * 16 + lr, ks * 32 + lg * 8)];
        }
        #pragma unroll
        for (int nt = 0; nt < 8; nt++) {
            #pragma unroll
            for (int ks = 0; ks < 2; ks++) {
                f16x8 bh = *(const f16x8*)&W2h[sidx2(nt * 16 + lr, ks * 32 + lg * 8)];
                f16x8 bl = *(const f16x8*)&W2l[sidx2(nt * 16 + lr, ks * 32 + lg * 8)];
                acc2[nt] = __builtin_amdgcn_mfma_f32_16x16x32_f16(a2h[ks], bl, acc2[nt], 0, 0, 0);
                acc2[nt] = __builtin_amdgcn_mfma_f32_16x16x32_f16(a2l[ks], bh, acc2[nt], 0, 0, 0);
                acc2[nt] = __builtin_amdgcn_mfma_f32_16x16x32_f16(a2h[ks], bh, acc2[nt], 0, 0, 0);
            }
        }
    }
    __syncthreads();   // all GEMM2 LDS reads done; region becomes xs2

    // ---- GN2 (wave-local, 32-ch groups) + ReLU -> Xh/Xl ----
    {
        float bi2[8], gg2[8], bb2[8];
        #pragma unroll
        for (int nt = 0; nt < 8; nt++) {
            int n = nt * 16 + lr;
            bi2[nt] = b_in1[n]; gg2[nt] = g_in1[n]; bb2[nt] = be_in1[n];
        }
        #pragma unroll
        for (int r = 0; r < 4; r++) {
            float vv[8];
            #pragma unroll
            for (int nt = 0; nt < 8; nt++) vv[nt] = acc2[nt][r] + bi2[nt];
            float mus[4], rss[4];
            #pragma unroll
            for (int g = 0; g < 4; g++) {
                float s = vv[2 * g] + vv[2 * g + 1];
                float s2 = vv[2 * g] * vv[2 * g] + vv[2 * g + 1] * vv[2 * g + 1];
                #pragma unroll
                for (int mk = 1; mk <= 8; mk <<= 1) { s += __shfl_xor(s, mk); s2 += __shfl_xor(s2, mk); }
                mus[g] = s * (1.f / 32.f);
                rss[g] = rsqrtf(s2 * (1.f / 32.f) - mus[g] * mus[g] + EPS);
            }
            int row = w * 16 + lg * 4 + r;
            #pragma unroll
            for (int nt = 0; nt < 8; nt++) {
                int g = nt >> 1;
                float hv = fmaxf(fmaf((vv[nt] - mus[g]) * rss[g], gg2[nt], bb2[nt]), 0.f);
                _Float16 h16 = (_Float16)hv;
                int ii = sidx(row, nt * 16 + lr);
                Xh[ii] = __builtin_bit_cast(ushort_t, h16);
                Xl[ii] = __builtin_bit_cast(ushort_t, (_Float16)(hv - (float)h16));
            }
        }
    }
    __syncthreads();

    // ---- in_norm stats: waves 0..3 -> pixel w; 4 lanes per group ----
    if (w < 4) {
        int g = l >> 2, j = l & 3;
        float s = 0.f, s2 = 0.f;
        #pragma unroll
        for (int k = 0; k < 48; k++) {
            int e = j * 48 + k;
            int t = e >> 3, co = e & 7;
            int ii = sidx(w * 24 + t, g * 8 + co);
            float v = (float)__builtin_bit_cast(_Float16, Xh[ii]) +
                      (float)__builtin_bit_cast(_Float16, Xl[ii]);
            s += v; s2 += v * v;
        }
        s += __shfl_xor(s, 1);  s += __shfl_xor(s, 2);
        s2 += __shfl_xor(s2, 1); s2 += __shfl_xor(s2, 2);
        if (j == 0) {
            float mu = s * (1.f / 192.f);
            muS[w][g] = mu;
            rsS[w][g] = rsqrtf(s2 * (1.f / 192.f) - mu * mu + EPS);
        }
    }
    __syncthreads();

    // ---- apply in_norm + PE ----
    for (int i = tid; i < 96 * 128; i += 384) {
        int row = i >> 7, c = i & 127;
        int px = row / 24, t = row - px * 24;
        int ii = sidx(row, c);
        float v = (float)__builtin_bit_cast(_Float16, Xh[ii]) +
                  (float)__builtin_bit_cast(_Float16, Xl[ii]);
        v = (v - muS[px][c >> 3]) * rsS[px][c >> 3] * g_innorm[c] + b_innorm[c] + peS[t][c & 7];
        _Float16 h16 = (_Float16)v;
        Xh[ii] = __builtin_bit_cast(ushort_t, h16);
        Xl[ii] = __builtin_bit_cast(ushort_t, (_Float16)(v - (float)h16));
    }
    __syncthreads();

    // ---- scores via split-fp16 MFMA: 6 waves = 6 m-tiles ----
    {
        f16x8 qh[4], ql[4];
        #pragma unroll
        for (int ks = 0; ks < 4; ks++) {
            qh[ks] = *(const f16x8*)(qkBh + ((ks * 4 + lg) * 16 + lr) * 8);
            ql[ks] = *(const f16x8*)(qkBl + ((ks * 4 + lg) * 16 + lr) * 8);
        }
        f32x4 sacc = f32x4{0.f, 0.f, 0.f, 0.f};
        #pragma unroll
        for (int ks = 0; ks < 4; ks++) {
            f16x8 ah = *(const f16x8*)&Xh[sidx(w * 16 + lr, ks * 32 + lg * 8)];
            f16x8 al = *(const f16x8*)&Xl[sidx(w * 16 + lr, ks * 32 + lg * 8)];
            sacc = __builtin_amdgcn_mfma_f32_16x16x32_f16(ah, ql[ks], sacc, 0, 0, 0);
            sacc = __builtin_amdgcn_mfma_f32_16x16x32_f16(al, qh[ks], sacc, 0, 0, 0);
            sacc = __builtin_amdgcn_mfma_f32_16x16x32_f16(ah, qh[ks], sacc, 0, 0, 0);
        }
        float qb = qb2G[lr];
        #pragma unroll
        for (int r = 0; r < 4; r++) {
            int row = w * 16 + lg * 4 + r;
            int px = row / 24, t = row - px * 24;
            scP[(px * 16 + lr) * 24 + t] = sacc[r] + qb;
        }
    }
    __syncthreads();

    // ---- softmax: 4 threads per (pixel, head) ----
    if (tid < 256) {
        int task = tid >> 2;                 // 0..63 = px*16 + h
        int px = task >> 4, h = task & 15, j = tid & 3;
        float* sp = scP + (px * 16 + h) * 24;
        float mx = -1e30f;
        #pragma unroll
        for (int k = 0; k < 6; k++) mx = fmaxf(mx, sp[j + 4 * k]);
        mx = fmaxf(mx, __shfl_xor(mx, 1));
        mx = fmaxf(mx, __shfl_xor(mx, 2));
        float ev[6], sum = 0.f;
        #pragma unroll
        for (int k = 0; k < 6; k++) { ev[k] = __expf(sp[j + 4 * k] - mx); sum += ev[k]; }
        sum += __shfl_xor(sum, 1);
        sum += __shfl_xor(sum, 2);
        float inv = 1.f / sum;
        #pragma unroll
        for (int k = 0; k < 6; k++) sp[j + 4 * k] = ev[k] * inv;
    }
    __syncthreads();

    // ---- o = a . v ----
    #pragma unroll
    for (int k = 0; k < 2; k++) {
        int task = tid + k * 384;
        if (task < 512) {
            int px = task >> 7, ch = task & 127;
            int h = ch >> 3;
            const float* sp = scP + (px * 16 + h) * 24;
            float s = 0.f;
            #pragma unroll
            for (int t = 0; t < 24; t++) {
                int ii = sidx(px * 24 + t, ch);
                float v = (float)__builtin_bit_cast(_Float16, Xh[ii]) +
                          (float)__builtin_bit_cast(_Float16, Xl[ii]);
                s = fmaf(sp[t], v, s);
            }
            ovP[px * 128 + ch] = s;
        }
    }
    __syncthreads();

    // ---- MLP layer 1 (128->256) + GN(4/64) + ReLU ----
    #pragma unroll
    for (int k = 0; k < 3; k++) {
        int i = tid + k * 384;
        if (i < 1024) {
            int px = i >> 8, o = i & 255;
            const float* wr = w_m0 + o * 128;
            float acc = 0.f;
            for (int c0 = 0; c0 < 128; c0 += 4) {
                float4 w4 = *(const float4*)(wr + c0);
                float4 x4 = *(const float4*)(ovP + px * 128 + c0);
                acc = fmaf(w4.x, x4.x, acc); acc = fmaf(w4.y, x4.y, acc);
                acc = fmaf(w4.z, x4.z, acc); acc = fmaf(w4.w, x4.w, acc);
            }
            float v = acc + b_m0[o];
            float s = v, s2 = v * v;
            #pragma unroll
            for (int mk = 1; mk <= 32; mk <<= 1) { s += __shfl_xor(s, mk); s2 += __shfl_xor(s2, mk); }
            float mu = s * (1.f / 64.f);
            float rs = rsqrtf(s2 * (1.f / 64.f) - mu * mu + EPS);
            mmP[px * 256 + o] = fmaxf(fmaf((v - mu) * rs, g_m0[o], be_m0[o]), 0.f);
        }
        __syncthreads();
    }

    // ---- MLP layer 2 (256->128) + GN(4/32) + ReLU + out_norm GN(16/8) ----
    #pragma unroll
    for (int k = 0; k < 2; k++) {
        int i = tid + k * 384;
        if (i < 512) {
            int px = i >> 7, o = i & 127;
            const float* wr = w_m1 + o * 256;
            float acc = 0.f;
            for (int c0 = 0; c0 < 256; c0 += 4) {
                float4 w4 = *(const float4*)(wr + c0);
                float4 x4 = *(const float4*)(mmP + px * 256 + c0);
                acc = fmaf(w4.x, x4.x, acc); acc = fmaf(w4.y, x4.y, acc);
                acc = fmaf(w4.z, x4.z, acc); acc = fmaf(w4.w, x4.w, acc);
            }
            float v = acc + b_m1[o];
            float s = v, s2 = v * v;
            #pragma unroll
            for (int mk = 1; mk <= 16; mk <<= 1) { s += __shfl_xor(s, mk); s2 += __shfl_xor(s2, mk); }
            float mu = s * (1.f / 32.f);
            float rs = rsqrtf(s2 * (1.f / 32.f) - mu * mu + EPS);
            float v2 = fmaxf(fmaf((v - mu) * rs, g_m1[o], be_m1[o]), 0.f);
            float t1 = v2, t2 = v2 * v2;
            #pragma unroll
            for (int mk = 1; mk <= 4; mk <<= 1) { t1 += __shfl_xor(t1, mk); t2 += __shfl_xor(t2, mk); }
            float mu2 = t1 * (1.f / 8.f);
            float rs2 = rsqrtf(t2 * (1.f / 8.f) - mu2 * mu2 + EPS);
            ysP[px * 128 + o] = fmaf((v2 - mu2) * rs2, g_out[o], b_out[o]);
        }
    }
    __syncthreads();

    // ---- store: float4 across the block's 4 consecutive pixels ----
    if (tid < 128) {
        float4 y4;
        y4.x = ysP[0 * 128 + tid]; y4.y = ysP[1 * 128 + tid];
        y4.z = ysP[2 * 128 + tid]; y4.w = ysP[3 * 128 + tid];
        *(float4*)(out + ((size_t)(b * 128 + tid)) * HWp + pixbase) = y4;
    }
}

extern "C" void kernel_launch(void* const* d_in, const int* in_sizes, int n_in,
                              void* d_out, int out_size, void* d_ws, size_t ws_size,
                              hipStream_t stream) {
    const float* x        = (const float*)d_in[0];
    const int*   bpos     = (const int*)  d_in[1];
    const float* w_in0    = (const float*)d_in[2];
    const float* b_in0    = (const float*)d_in[3];
    const float* g_in0    = (const float*)d_in[4];
    const float* be_in0   = (const float*)d_in[5];
    const float* w_in1    = (const float*)d_in[6];
    const float* b_in1    = (const float*)d_in[7];
    const float* g_in1    = (const float*)d_in[8];
    const float* be_in1   = (const float*)d_in[9];
    const float* g_innorm = (const float*)d_in[10];
    const float* b_innorm = (const float*)d_in[11];
    const float* Qm       = (const float*)d_in[12];
    const float* w_k      = (const float*)d_in[13];
    const float* b_k      = (const float*)d_in[14];
    const float* w_m0     = (const float*)d_in[15];
    const float* b_m0     = (const float*)d_in[16];
    const float* g_m0     = (const float*)d_in[17];
    const float* be_m0    = (const float*)d_in[18];
    const float* w_m1     = (const float*)d_in[19];
    const float* b_m1     = (const float*)d_in[20];
    const float* g_m1     = (const float*)d_in[21];
    const float* be_m1    = (const float*)d_in[22];
    const float* g_out    = (const float*)d_in[23];
    const float* b_out    = (const float*)d_in[24];

    _Float16* w1h  = (_Float16*)d_ws;
    _Float16* w1l  = w1h + 32768;
    _Float16* w2h  = w1l + 32768;
    _Float16* w2l  = w2h + 32768;
    _Float16* qkBh = (_Float16*)((char*)d_ws + 262144);
    _Float16* qkBl = qkBh + 2048;
    float*    qb2G = (float*)((char*)d_ws + 270336);
    float*    peG  = (float*)((char*)d_ws + 270400);
    ushort_t* xph  = (ushort_t*)((char*)d_ws + XPH_OFF);
    ushort_t* xpl  = (ushort_t*)((char*)d_ws + XPL_OFF);

    const int packed = (ws_size >= WS_NEEDED) ? 1 : 0;

    hipLaunchKernelGGL(ltae_prep, dim3(268), dim3(256), 0, stream,
                       w_in0, w_in1, Qm, w_k, b_k, bpos,
                       w1h, w1l, w2h, w2l, qkBh, qkBl, qb2G, peG);

    if (packed) {
        hipLaunchKernelGGL(ltae_pack, dim3(3456), dim3(256), 0, stream, x, xph, xpl);
    }

    hipLaunchKernelGGL(ltae_main, dim3(2304), dim3(384), 0, stream,
                       x, xph, xpl, packed,
                       b_in0, g_in0, be_in0,
                       b_in1, g_in1, be_in1,
                       g_innorm, b_innorm,
                       w_m0, b_m0, g_m0, be_m0,
                       w_m1, b_m1, g_m1, be_m1,
                       g_out, b_out,
                       w1h, w1l, w2h, w2l, qkBh, qkBl, qb2G, peG,
                       (float*)d_out);
}

// Round 7
// 569.414 us; speedup vs baseline: 1.1230x; 1.1230x over previous
//
#include <hip/hip_runtime.h>
#include <math.h>

typedef _Float16 f16x8 __attribute__((ext_vector_type(8)));
typedef float f32x4 __attribute__((ext_vector_type(4)));
typedef unsigned short ushort_t;

constexpr int HWp = 2304;
constexpr float EPS = 1e-5f;

// swizzled ushort index, 256B rows (128 fp16 cols): byte = row*256 + ((c*2)^((row&7)<<4))
__device__ __forceinline__ int sidx(int row, int c) {
    return ((row << 8) + ((c << 1) ^ ((row & 7) << 4))) >> 1;
}

// ---------------- prep: weights -> split fp16 (hi/lo), fold Q+scale, PE table ----------------
__global__ void ltae_prep(const float* __restrict__ w_in0, const float* __restrict__ w_in1,
                          const float* __restrict__ Qm, const float* __restrict__ w_k,
                          const float* __restrict__ b_k, const int* __restrict__ bpos,
                          _Float16* __restrict__ w1h, _Float16* __restrict__ w1l,
                          _Float16* __restrict__ w2h, _Float16* __restrict__ w2l,
                          _Float16* __restrict__ qkBh, _Float16* __restrict__ qkBl,
                          float* __restrict__ qb2G, float* __restrict__ peG) {
    int i = blockIdx.x * 256 + threadIdx.x;
    if (i < 32768) {
        float v = w_in0[i];
        _Float16 h = (_Float16)v;
        w1h[i] = h; w1l[i] = (_Float16)(v - (float)h);
    } else if (i < 65536) {
        int j = i - 32768;
        float v = w_in1[j];
        _Float16 h = (_Float16)v;
        w2h[j] = h; w2l[j] = (_Float16)(v - (float)h);
    } else if (i < 67584) {
        int j = i - 65536; int h = j >> 7, k = j & 127;
        float s = 0.f;
        #pragma unroll
        for (int dk = 0; dk < 4; dk++) s = fmaf(Qm[h * 4 + dk], w_k[(h * 4 + dk) * 128 + k], s);
        s *= 0.5f;
        _Float16 hi = (_Float16)s;
        int ks = k >> 5, lg = (k >> 3) & 3, jj = k & 7;
        int pos = ((ks * 4 + lg) * 16 + h) * 8 + jj;
        qkBh[pos] = hi; qkBl[pos] = (_Float16)(s - (float)hi);
    } else if (i < 67600) {
        int h = i - 67584;
        float s = 0.f;
        #pragma unroll
        for (int dk = 0; dk < 4; dk++) s = fmaf(Qm[h * 4 + dk], b_k[h * 4 + dk], s);
        qb2G[h] = 0.5f * s;
    } else if (i < 68368) {
        int j = i - 67600;
        int bb = j / 192, r = j - bb * 192;
        int t = r >> 3, d = r & 7;
        const float dens[4] = {1.0f, 5.623413251903491f, 31.622776601683793f, 177.82794100389228f};
        float ang = (float)bpos[bb * 24 + t] / dens[d >> 1];
        peG[j] = (d & 1) ? cosf(ang) : sinf(ang);
    }
}

// ---------------- main: 2 pixels per 8-wave block, 3 blocks/CU ----------------
__global__ __launch_bounds__(512, 6) void ltae_main(
    const float* __restrict__ x,
    const float* __restrict__ b_in0, const float* __restrict__ g_in0, const float* __restrict__ be_in0,
    const float* __restrict__ b_in1, const float* __restrict__ g_in1, const float* __restrict__ be_in1,
    const float* __restrict__ g_innorm, const float* __restrict__ b_innorm,
    const float* __restrict__ w_m0, const float* __restrict__ b_m0,
    const float* __restrict__ g_m0, const float* __restrict__ be_m0,
    const float* __restrict__ w_m1, const float* __restrict__ b_m1,
    const float* __restrict__ g_m1, const float* __restrict__ be_m1,
    const float* __restrict__ g_out, const float* __restrict__ b_out,
    const _Float16* __restrict__ w1h, const _Float16* __restrict__ w1l,
    const _Float16* __restrict__ w2h, const _Float16* __restrict__ w2l,
    const _Float16* __restrict__ qkBh, const _Float16* __restrict__ qkBl,
    const float* __restrict__ qb2G, const float* __restrict__ peG,
    float* __restrict__ out)
{
    __shared__ __align__(16) ushort_t Ah[48 * 128], Al[48 * 128];  // tokens, later xs2 hi/lo
    __shared__ __align__(16) ushort_t Hh[48 * 128], Hl[48 * 128];  // h1 half-tile hi/lo
    __shared__ float peS[24][8];
    __shared__ float muS[2][16], rsS[2][16];
    __shared__ float2 partS[384];     // [wave][m][lg][r] GN partials

    float* scP = (float*)Hh;          // [2][16][24] overlays H after GEMMs
    float* ovP = scP + 768;           // [2][128]
    float* mmP = ovP + 256;           // [2][256]
    float* ysP = scP;                 // reuse after a.v

    const int tid = threadIdx.x;
    const int bid = blockIdx.x;
    const int sb  = (bid & 7) * 576 + (bid >> 3);   // bijective XCD swizzle (4608 = 8*576)
    const int b   = sb / 1152;
    const int pixbase = (sb - b * 1152) * 2;
    const int w  = tid >> 6;
    const int l  = tid & 63;
    const int lr = l & 15;
    const int lg = l >> 4;

    // ---- Phase 0: PE cache + gather tokens -> Ah/Al (split fp16, swizzled) ----
    if (tid < 192) peS[tid >> 3][tid & 7] = peG[b * 192 + tid];
    for (int i = tid; i < 24 * 128; i += 512) {
        int t = i >> 7, c = i & 127;
        const float* gp = x + ((size_t)((b * 24 + t) * 128 + c)) * HWp + pixbase;
        float2 v = *(const float2*)gp;
        _Float16 h0 = (_Float16)v.x;
        _Float16 h1 = (_Float16)v.y;
        int i0 = sidx(t, c), i1 = sidx(24 + t, c);
        Ah[i0] = __builtin_bit_cast(ushort_t, h0);
        Al[i0] = __builtin_bit_cast(ushort_t, (_Float16)(v.x - (float)h0));
        Ah[i1] = __builtin_bit_cast(ushort_t, h1);
        Al[i1] = __builtin_bit_cast(ushort_t, (_Float16)(v.y - (float)h1));
    }
    __syncthreads();

    // ---- GEMM1 (two N-halves) + GEMM2 (partial-accumulate over K-halves) ----
    f32x4 acc2[3];
    #pragma unroll
    for (int m = 0; m < 3; m++) acc2[m] = f32x4{0.f, 0.f, 0.f, 0.f};
    const int n2 = w * 16 + lr;           // GEMM2 output channel

    #pragma unroll 1
    for (int half = 0; half < 2; half++) {
        const int n1 = half * 128 + w * 16 + lr;   // GEMM1 output channel
        f16x8 bh[4], bl[4];
        #pragma unroll
        for (int ks = 0; ks < 4; ks++) {
            bh[ks] = *(const f16x8*)(w1h + n1 * 128 + ks * 32 + lg * 8);
            bl[ks] = *(const f16x8*)(w1l + n1 * 128 + ks * 32 + lg * 8);
        }
        const float bi1 = b_in0[n1], gg1 = g_in0[n1], bb1 = be_in0[n1];

        f32x4 acc1[3];
        #pragma unroll
        for (int m = 0; m < 3; m++) acc1[m] = f32x4{0.f, 0.f, 0.f, 0.f};
        #pragma unroll
        for (int m = 0; m < 3; m++) {
            #pragma unroll
            for (int ks = 0; ks < 4; ks++) {
                f16x8 ah = *(const f16x8*)&Ah[sidx(m * 16 + lr, ks * 32 + lg * 8)];
                f16x8 al = *(const f16x8*)&Al[sidx(m * 16 + lr, ks * 32 + lg * 8)];
                acc1[m] = __builtin_amdgcn_mfma_f32_16x16x32_f16(ah, bl[ks], acc1[m], 0, 0, 0);
                acc1[m] = __builtin_amdgcn_mfma_f32_16x16x32_f16(al, bh[ks], acc1[m], 0, 0, 0);
                acc1[m] = __builtin_amdgcn_mfma_f32_16x16x32_f16(ah, bh[ks], acc1[m], 0, 0, 0);
            }
        }
        // GN1 (4-wave 64-ch groups) partials
        #pragma unroll
        for (int m = 0; m < 3; m++) {
            #pragma unroll
            for (int r = 0; r < 4; r++) {
                float v = acc1[m][r] + bi1;
                float s = v, s2 = v * v;
                #pragma unroll
                for (int mk = 1; mk <= 8; mk <<= 1) { s += __shfl_xor(s, mk); s2 += __shfl_xor(s2, mk); }
                if (lr == 0) partS[w * 48 + m * 16 + lg * 4 + r] = make_float2(s, s2);
            }
        }
        __syncthreads();
        const int wb = w & 4;
        #pragma unroll
        for (int m = 0; m < 3; m++) {
            #pragma unroll
            for (int r = 0; r < 4; r++) {
                int idx = m * 16 + lg * 4 + r;
                float st = 0.f, s2t = 0.f;
                #pragma unroll
                for (int j = 0; j < 4; j++) {
                    float2 q = partS[(wb + j) * 48 + idx];
                    st += q.x; s2t += q.y;
                }
                float mu = st * (1.f / 64.f);
                float rs = rsqrtf(s2t * (1.f / 64.f) - mu * mu + EPS);
                float v = acc1[m][r] + bi1;
                float hv = fmaxf(fmaf((v - mu) * rs, gg1, bb1), 0.f);
                _Float16 h16 = (_Float16)hv;
                int ii = sidx(idx, w * 16 + lr);
                Hh[ii] = __builtin_bit_cast(ushort_t, h16);
                Hl[ii] = __builtin_bit_cast(ushort_t, (_Float16)(hv - (float)h16));
            }
        }
        __syncthreads();

        // GEMM2 partial: K-slice = this half's 128 channels
        f16x8 b2h[4], b2l[4];
        #pragma unroll
        for (int ks = 0; ks < 4; ks++) {
            b2h[ks] = *(const f16x8*)(w2h + n2 * 256 + half * 128 + ks * 32 + lg * 8);
            b2l[ks] = *(const f16x8*)(w2l + n2 * 256 + half * 128 + ks * 32 + lg * 8);
        }
        #pragma unroll
        for (int m = 0; m < 3; m++) {
            #pragma unroll
            for (int ks = 0; ks < 4; ks++) {
                f16x8 ah = *(const f16x8*)&Hh[sidx(m * 16 + lr, ks * 32 + lg * 8)];
                f16x8 al = *(const f16x8*)&Hl[sidx(m * 16 + lr, ks * 32 + lg * 8)];
                acc2[m] = __builtin_amdgcn_mfma_f32_16x16x32_f16(ah, b2l[ks], acc2[m], 0, 0, 0);
                acc2[m] = __builtin_amdgcn_mfma_f32_16x16x32_f16(al, b2h[ks], acc2[m], 0, 0, 0);
                acc2[m] = __builtin_amdgcn_mfma_f32_16x16x32_f16(ah, b2h[ks], acc2[m], 0, 0, 0);
            }
        }
        __syncthreads();   // H reads done; region reusable next half
    }

    // ---- GN2 (2-wave 32-ch groups) + ReLU -> xs2 (A region) ----
    {
        const float bi2 = b_in1[n2], gg2 = g_in1[n2], bb2 = be_in1[n2];
        #pragma unroll
        for (int m = 0; m < 3; m++) {
            #pragma unroll
            for (int r = 0; r < 4; r++) {
                float v = acc2[m][r] + bi2;
                float s = v, s2 = v * v;
                #pragma unroll
                for (int mk = 1; mk <= 8; mk <<= 1) { s += __shfl_xor(s, mk); s2 += __shfl_xor(s2, mk); }
                if (lr == 0) partS[w * 48 + m * 16 + lg * 4 + r] = make_float2(s, s2);
            }
        }
        __syncthreads();
        #pragma unroll
        for (int m = 0; m < 3; m++) {
            #pragma unroll
            for (int r = 0; r < 4; r++) {
                int idx = m * 16 + lg * 4 + r;
                float2 q0 = partS[w * 48 + idx];
                float2 q1 = partS[(w ^ 1) * 48 + idx];
                float st = q0.x + q1.x, s2t = q0.y + q1.y;
                float mu = st * (1.f / 32.f);
                float rs = rsqrtf(s2t * (1.f / 32.f) - mu * mu + EPS);
                float v = acc2[m][r] + bi2;
                float hv = fmaxf(fmaf((v - mu) * rs, gg2, bb2), 0.f);
                _Float16 h16 = (_Float16)hv;
                int ii = sidx(idx, n2);
                Ah[ii] = __builtin_bit_cast(ushort_t, h16);
                Al[ii] = __builtin_bit_cast(ushort_t, (_Float16)(hv - (float)h16));
            }
        }
    }
    __syncthreads();

    // ---- in_norm stats: all 8 waves; wave w -> pixel w>>2, groups (w&3)*4+lg ----
    {
        const int p = w >> 2;
        const int g = (w & 3) * 4 + lg;
        float s = 0.f, s2 = 0.f;
        #pragma unroll
        for (int k = 0; k < 12; k++) {
            int e = lr + 16 * k;              // 0..191
            int t = e >> 3, co = e & 7;
            int ii = sidx(p * 24 + t, g * 8 + co);
            float v = (float)__builtin_bit_cast(_Float16, Ah[ii]) +
                      (float)__builtin_bit_cast(_Float16, Al[ii]);
            s += v; s2 += v * v;
        }
        #pragma unroll
        for (int mk = 1; mk <= 8; mk <<= 1) { s += __shfl_xor(s, mk); s2 += __shfl_xor(s2, mk); }
        if (lr == 0) {
            float mu = s * (1.f / 192.f);
            muS[p][g] = mu;
            rsS[p][g] = rsqrtf(s2 * (1.f / 192.f) - mu * mu + EPS);
        }
    }
    __syncthreads();

    // ---- apply in_norm + PE ----
    for (int i = tid; i < 48 * 128; i += 512) {
        int row = i >> 7, c = i & 127;
        int p = row >= 24 ? 1 : 0;
        int t = row - p * 24;
        int ii = sidx(row, c);
        float v = (float)__builtin_bit_cast(_Float16, Ah[ii]) +
                  (float)__builtin_bit_cast(_Float16, Al[ii]);
        v = (v - muS[p][c >> 3]) * rsS[p][c >> 3] * g_innorm[c] + b_innorm[c] + peS[t][c & 7];
        _Float16 h16 = (_Float16)v;
        Ah[ii] = __builtin_bit_cast(ushort_t, h16);
        Al[ii] = __builtin_bit_cast(ushort_t, (_Float16)(v - (float)h16));
    }
    __syncthreads();

    // ---- scores via split-fp16 MFMA (waves 0..2 = 3 m-tiles) ----
    if (w < 3) {
        const int m = w;
        f16x8 qh[4], ql[4];
        #pragma unroll
        for (int ks = 0; ks < 4; ks++) {
            qh[ks] = *(const f16x8*)(qkBh + ((ks * 4 + lg) * 16 + lr) * 8);
            ql[ks] = *(const f16x8*)(qkBl + ((ks * 4 + lg) * 16 + lr) * 8);
        }
        f32x4 sacc = f32x4{0.f, 0.f, 0.f, 0.f};
        #pragma unroll
        for (int ks = 0; ks < 4; ks++) {
            f16x8 ah = *(const f16x8*)&Ah[sidx(m * 16 + lr, ks * 32 + lg * 8)];
            f16x8 al = *(const f16x8*)&Al[sidx(m * 16 + lr, ks * 32 + lg * 8)];
            sacc = __builtin_amdgcn_mfma_f32_16x16x32_f16(ah, ql[ks], sacc, 0, 0, 0);
            sacc = __builtin_amdgcn_mfma_f32_16x16x32_f16(al, qh[ks], sacc, 0, 0, 0);
            sacc = __builtin_amdgcn_mfma_f32_16x16x32_f16(ah, qh[ks], sacc, 0, 0, 0);
        }
        float qb = qb2G[lr];
        #pragma unroll
        for (int r = 0; r < 4; r++) {
            int row = m * 16 + lg * 4 + r;
            int p = row >= 24 ? 1 : 0;
            int t = row - p * 24;
            scP[(p * 16 + lr) * 24 + t] = sacc[r] + qb;
        }
    }
    __syncthreads();

    // ---- softmax: waves 0..3; wave w -> pixel w>>1, heads (w&1)*8 + l>>3 ----
    if (w < 4) {
        const int p = w >> 1;
        int h = (w & 1) * 8 + (l >> 3), j = l & 7;
        float* sp = scP + (p * 16 + h) * 24;
        float mx = -1e30f;
        #pragma unroll
        for (int k = 0; k < 3; k++) mx = fmaxf(mx, sp[j + 8 * k]);
        mx = fmaxf(mx, __shfl_xor(mx, 1));
        mx = fmaxf(mx, __shfl_xor(mx, 2));
        mx = fmaxf(mx, __shfl_xor(mx, 4));
        float ev[3], sum = 0.f;
        #pragma unroll
        for (int k = 0; k < 3; k++) { ev[k] = __expf(sp[j + 8 * k] - mx); sum += ev[k]; }
        sum += __shfl_xor(sum, 1);
        sum += __shfl_xor(sum, 2);
        sum += __shfl_xor(sum, 4);
        float inv = 1.f / sum;
        #pragma unroll
        for (int k = 0; k < 3; k++) sp[j + 8 * k] = ev[k] * inv;
    }
    __syncthreads();

    // ---- o = a . v (256 tasks) ----
    if (tid < 256) {
        int px = tid >> 7, ch = tid & 127;
        int h = ch >> 3;
        const float* sp = scP + (px * 16 + h) * 24;
        float s = 0.f;
        #pragma unroll
        for (int t = 0; t < 24; t++) {
            int ii = sidx(px * 24 + t, ch);
            float v = (float)__builtin_bit_cast(_Float16, Ah[ii]) +
                      (float)__builtin_bit_cast(_Float16, Al[ii]);
            s = fmaf(sp[t], v, s);
        }
        ovP[px * 128 + ch] = s;
    }
    __syncthreads();

    // ---- MLP layer 1 (128->256) + GN(4/64) + ReLU: 512 tasks ----
    {
        int px = tid >> 8, o = tid & 255;
        const float* wr = w_m0 + o * 128;
        float acc = 0.f;
        for (int c0 = 0; c0 < 128; c0 += 4) {
            float4 w4 = *(const float4*)(wr + c0);
            float4 x4 = *(const float4*)(ovP + px * 128 + c0);
            acc = fmaf(w4.x, x4.x, acc); acc = fmaf(w4.y, x4.y, acc);
            acc = fmaf(w4.z, x4.z, acc); acc = fmaf(w4.w, x4.w, acc);
        }
        float v = acc + b_m0[o];
        float s = v, s2 = v * v;
        #pragma unroll
        for (int mk = 1; mk <= 32; mk <<= 1) { s += __shfl_xor(s, mk); s2 += __shfl_xor(s2, mk); }
        float mu = s * (1.f / 64.f);
        float rs = rsqrtf(s2 * (1.f / 64.f) - mu * mu + EPS);
        mmP[px * 256 + o] = fmaxf(fmaf((v - mu) * rs, g_m0[o], be_m0[o]), 0.f);
    }
    __syncthreads();

    // ---- MLP layer 2 (256->128) + GN(4/32) + ReLU + out_norm GN(16/8): 256 tasks ----
    if (tid < 256) {
        int px = tid >> 7, o = tid & 127;
        const float* wr = w_m1 + o * 256;
        float acc = 0.f;
        for (int c0 = 0; c0 < 256; c0 += 4) {
            float4 w4 = *(const float4*)(wr + c0);
            float4 x4 = *(const float4*)(mmP + px * 256 + c0);
            acc = fmaf(w4.x, x4.x, acc); acc = fmaf(w4.y, x4.y, acc);
            acc = fmaf(w4.z, x4.z, acc); acc = fmaf(w4.w, x4.w, acc);
        }
        float v = acc + b_m1[o];
        float s = v, s2 = v * v;
        #pragma unroll
        for (int mk = 1; mk <= 16; mk <<= 1) { s += __shfl_xor(s, mk); s2 += __shfl_xor(s2, mk); }
        float mu = s * (1.f / 32.f);
        float rs = rsqrtf(s2 * (1.f / 32.f) - mu * mu + EPS);
        float v2 = fmaxf(fmaf((v - mu) * rs, g_m1[o], be_m1[o]), 0.f);
        float t1 = v2, t2 = v2 * v2;
        #pragma unroll
        for (int mk = 1; mk <= 4; mk <<= 1) { t1 += __shfl_xor(t1, mk); t2 += __shfl_xor(t2, mk); }
        float mu2 = t1 * (1.f / 8.f);
        float rs2 = rsqrtf(t2 * (1.f / 8.f) - mu2 * mu2 + EPS);
        ysP[px * 128 + o] = fmaf((v2 - mu2) * rs2, g_out[o], b_out[o]);
    }
    __syncthreads();

    // ---- store (float2 across the 2 pixels) ----
    if (tid < 128) {
        float2 y2;
        y2.x = ysP[0 * 128 + tid];
        y2.y = ysP[1 * 128 + tid];
        *(float2*)(out + ((size_t)(b * 128 + tid)) * HWp + pixbase) = y2;
    }
}

extern "C" void kernel_launch(void* const* d_in, const int* in_sizes, int n_in,
                              void* d_out, int out_size, void* d_ws, size_t ws_size,
                              hipStream_t stream) {
    const float* x        = (const float*)d_in[0];
    const int*   bpos     = (const int*)  d_in[1];
    const float* w_in0    = (const float*)d_in[2];
    const float* b_in0    = (const float*)d_in[3];
    const float* g_in0    = (const float*)d_in[4];
    const float* be_in0   = (const float*)d_in[5];
    const float* w_in1    = (const float*)d_in[6];
    const float* b_in1    = (const float*)d_in[7];
    const float* g_in1    = (const float*)d_in[8];
    const float* be_in1   = (const float*)d_in[9];
    const float* g_innorm = (const float*)d_in[10];
    const float* b_innorm = (const float*)d_in[11];
    const float* Qm       = (const float*)d_in[12];
    const float* w_k      = (const float*)d_in[13];
    const float* b_k      = (const float*)d_in[14];
    const float* w_m0     = (const float*)d_in[15];
    const float* b_m0     = (const float*)d_in[16];
    const float* g_m0     = (const float*)d_in[17];
    const float* be_m0    = (const float*)d_in[18];
    const float* w_m1     = (const float*)d_in[19];
    const float* b_m1     = (const float*)d_in[20];
    const float* g_m1     = (const float*)d_in[21];
    const float* be_m1    = (const float*)d_in[22];
    const float* g_out    = (const float*)d_in[23];
    const float* b_out    = (const float*)d_in[24];

    // ws layout (bytes): w1h@0, w1l@65536, w2h@131072, w2l@196608 (fp16, 32768 each)
    //                    qkBh@262144 (2048 fp16), qkBl@266240, qb2@270336, peG@270400
    _Float16* w1h  = (_Float16*)d_ws;
    _Float16* w1l  = w1h + 32768;
    _Float16* w2h  = w1l + 32768;
    _Float16* w2l  = w2h + 32768;
    _Float16* qkBh = (_Float16*)((char*)d_ws + 262144);
    _Float16* qkBl = qkBh + 2048;
    float*    qb2G = (float*)((char*)d_ws + 270336);
    float*    peG  = (float*)((char*)d_ws + 270400);

    hipLaunchKernelGGL(ltae_prep, dim3(268), dim3(256), 0, stream,
                       w_in0, w_in1, Qm, w_k, b_k, bpos,
                       w1h, w1l, w2h, w2l, qkBh, qkBl, qb2G, peG);

    hipLaunchKernelGGL(ltae_main, dim3(4608), dim3(512), 0, stream,
                       x,
                       b_in0, g_in0, be_in0,
                       b_in1, g_in1, be_in1,
                       g_innorm, b_innorm,
                       w_m0, b_m0, g_m0, be_m0,
                       w_m1, b_m1, g_m1, be_m1,
                       g_out, b_out,
                       w1h, w1l, w2h, w2l, qkBh, qkBl, qb2G, peG,
                       (float*)d_out);
}

// Round 9
// 510.817 us; speedup vs baseline: 1.2518x; 1.1147x over previous
//
#include <hip/hip_runtime.h>
#include <math.h>

typedef _Float16 f16x8 __attribute__((ext_vector_type(8)));
typedef float f32x4 __attribute__((ext_vector_type(4)));
typedef unsigned short ushort_t;

constexpr int HWp = 2304;
constexpr float EPS = 1e-5f;

// swizzled ushort index, 256B rows (128 fp16 cols): byte = row*256 + ((c*2)^((row&7)<<4))
__device__ __forceinline__ int sidx(int row, int c) {
    return ((row << 8) + ((c << 1) ^ ((row & 7) << 4))) >> 1;
}

// ---------------- prep: weights -> split fp16 (hi/lo), fold Q+scale, PE table ----------------
__global__ void ltae_prep(const float* __restrict__ w_in0, const float* __restrict__ w_in1,
                          const float* __restrict__ Qm, const float* __restrict__ w_k,
                          const float* __restrict__ b_k, const int* __restrict__ bpos,
                          _Float16* __restrict__ w1h, _Float16* __restrict__ w1l,
                          _Float16* __restrict__ w2h, _Float16* __restrict__ w2l,
                          _Float16* __restrict__ qkBh, _Float16* __restrict__ qkBl,
                          float* __restrict__ qb2G, float* __restrict__ peG) {
    int i = blockIdx.x * 256 + threadIdx.x;
    if (i < 32768) {
        float v = w_in0[i];
        _Float16 h = (_Float16)v;
        w1h[i] = h; w1l[i] = (_Float16)(v - (float)h);
    } else if (i < 65536) {
        int j = i - 32768;
        float v = w_in1[j];
        _Float16 h = (_Float16)v;
        w2h[j] = h; w2l[j] = (_Float16)(v - (float)h);
    } else if (i < 67584) {
        int j = i - 65536; int h = j >> 7, k = j & 127;
        float s = 0.f;
        #pragma unroll
        for (int dk = 0; dk < 4; dk++) s = fmaf(Qm[h * 4 + dk], w_k[(h * 4 + dk) * 128 + k], s);
        s *= 0.5f;
        _Float16 hi = (_Float16)s;
        int ks = k >> 5, lg = (k >> 3) & 3, jj = k & 7;
        int pos = ((ks * 4 + lg) * 16 + h) * 8 + jj;
        qkBh[pos] = hi; qkBl[pos] = (_Float16)(s - (float)hi);
    } else if (i < 67600) {
        int h = i - 67584;
        float s = 0.f;
        #pragma unroll
        for (int dk = 0; dk < 4; dk++) s = fmaf(Qm[h * 4 + dk], b_k[h * 4 + dk], s);
        qb2G[h] = 0.5f * s;
    } else if (i < 68368) {
        int j = i - 67600;
        int bb = j / 192, r = j - bb * 192;
        int t = r >> 3, d = r & 7;
        const float dens[4] = {1.0f, 5.623413251903491f, 31.622776601683793f, 177.82794100389228f};
        float ang = (float)bpos[bb * 24 + t] / dens[d >> 1];
        peG[j] = (d & 1) ? cosf(ang) : sinf(ang);
    }
}

// ---------------- main: 2 pixels per 4-wave block, 3 blocks/CU ----------------
__global__ __launch_bounds__(256, 3) void ltae_main(
    const float* __restrict__ x,
    const float* __restrict__ b_in0, const float* __restrict__ g_in0, const float* __restrict__ be_in0,
    const float* __restrict__ b_in1, const float* __restrict__ g_in1, const float* __restrict__ be_in1,
    const float* __restrict__ g_innorm, const float* __restrict__ b_innorm,
    const float* __restrict__ w_m0, const float* __restrict__ b_m0,
    const float* __restrict__ g_m0, const float* __restrict__ be_m0,
    const float* __restrict__ w_m1, const float* __restrict__ b_m1,
    const float* __restrict__ g_m1, const float* __restrict__ be_m1,
    const float* __restrict__ g_out, const float* __restrict__ b_out,
    const _Float16* __restrict__ w1h, const _Float16* __restrict__ w1l,
    const _Float16* __restrict__ w2h, const _Float16* __restrict__ w2l,
    const _Float16* __restrict__ qkBh, const _Float16* __restrict__ qkBl,
    const float* __restrict__ qb2G, const float* __restrict__ peG,
    float* __restrict__ out)
{
    __shared__ __align__(16) ushort_t Ah[48 * 128], Al[48 * 128];  // tokens, later xs2 hi/lo
    __shared__ __align__(16) ushort_t Hh[48 * 128], Hl[48 * 128];  // h1 half-tile hi/lo
    __shared__ float peS[24][8];
    __shared__ float2 partS[192];     // GN1 cross-wave partials

    float* scP = (float*)Hh;          // [2][16][24] overlays H after GEMMs
    float* ovP = scP + 768;           // [2][128]
    float* mmP = ovP + 256;           // [2][256]
    float* ysP = ovP;

    const int tid = threadIdx.x;
    const int bid = blockIdx.x;
    const int sb  = (bid & 7) * 576 + (bid >> 3);   // bijective XCD swizzle (4608 = 8*576)
    const int b   = sb / 1152;
    const int pixbase = (sb - b * 1152) * 2;
    const int w  = tid >> 6;
    const int l  = tid & 63;
    const int lr = l & 15;
    const int lg = l >> 4;

    // ---- top: issue half-0 weight loads + all per-thread scalars (complete at gather barrier) ----
    f16x8 bh0[2][4], bl0[2][4], c2h0[2][4], c2l0[2][4];
    float bi1A[2][2], gg1A[2][2], bb1A[2][2];
    const int cA = w * 32 + lr;            // nt=0 channel (GEMM2 out & GEMM1-in-half offset)
    const int cB = cA + 16;                // nt=1 channel
    #pragma unroll
    for (int nt = 0; nt < 2; nt++) {
        int n = cA + nt * 16;              // half0 GEMM1 channel
        #pragma unroll
        for (int ks = 0; ks < 4; ks++) {
            bh0[nt][ks]  = *(const f16x8*)(w1h + n * 128 + ks * 32 + lg * 8);
            bl0[nt][ks]  = *(const f16x8*)(w1l + n * 128 + ks * 32 + lg * 8);
            c2h0[nt][ks] = *(const f16x8*)(w2h + n * 256 + ks * 32 + lg * 8);
            c2l0[nt][ks] = *(const f16x8*)(w2l + n * 256 + ks * 32 + lg * 8);
        }
        bi1A[0][nt] = b_in0[n];       gg1A[0][nt] = g_in0[n];       bb1A[0][nt] = be_in0[n];
        bi1A[1][nt] = b_in0[n + 128]; gg1A[1][nt] = g_in0[n + 128]; bb1A[1][nt] = be_in0[n + 128];
    }
    float b2v[2] = {b_in1[cA], b_in1[cB]};
    float g2v[2] = {g_in1[cA], g_in1[cB]};
    float be2v[2] = {be_in1[cA], be_in1[cB]};
    float giV[2] = {g_innorm[cA], g_innorm[cB]};
    float biV[2] = {b_innorm[cA], b_innorm[cB]};

    // ---- gather tokens -> Ah/Al (split fp16, swizzled) + PE cache ----
    if (tid < 192) peS[tid >> 3][tid & 7] = peG[b * 192 + tid];
    for (int i = tid; i < 24 * 128; i += 256) {
        int t = i >> 7, c = i & 127;
        const float* gp = x + ((size_t)((b * 24 + t) * 128 + c)) * HWp + pixbase;
        float2 v = *(const float2*)gp;
        _Float16 h0 = (_Float16)v.x;
        _Float16 h1 = (_Float16)v.y;
        int i0 = sidx(t, c), i1 = sidx(24 + t, c);
        Ah[i0] = __builtin_bit_cast(ushort_t, h0);
        Al[i0] = __builtin_bit_cast(ushort_t, (_Float16)(v.x - (float)h0));
        Ah[i1] = __builtin_bit_cast(ushort_t, h1);
        Al[i1] = __builtin_bit_cast(ushort_t, (_Float16)(v.y - (float)h1));
    }
    __syncthreads();

    f32x4 acc2[3][2];
    #pragma unroll
    for (int m = 0; m < 3; m++)
        #pragma unroll
        for (int nt = 0; nt < 2; nt++) acc2[m][nt] = f32x4{0.f, 0.f, 0.f, 0.f};
    f16x8 bh1[2][4], bl1[2][4], c2h1[2][4], c2l1[2][4];   // half-1 prefetch targets

    auto do_half = [&](const f16x8 (&Wh)[2][4], const f16x8 (&Wl)[2][4],
                       const f16x8 (&Vh)[2][4], const f16x8 (&Vl)[2][4],
                       int half, bool prefetch_next) {
        // GEMM1: 48 tokens x 128 channels of this half
        f32x4 acc1[3][2];
        #pragma unroll
        for (int m = 0; m < 3; m++)
            #pragma unroll
            for (int nt = 0; nt < 2; nt++) acc1[m][nt] = f32x4{0.f, 0.f, 0.f, 0.f};
        #pragma unroll
        for (int m = 0; m < 3; m++) {
            #pragma unroll
            for (int ks = 0; ks < 4; ks++) {
                f16x8 ah = *(const f16x8*)&Ah[sidx(m * 16 + lr, ks * 32 + lg * 8)];
                f16x8 al = *(const f16x8*)&Al[sidx(m * 16 + lr, ks * 32 + lg * 8)];
                #pragma unroll
                for (int nt = 0; nt < 2; nt++) {
                    acc1[m][nt] = __builtin_amdgcn_mfma_f32_16x16x32_f16(ah, Wl[nt][ks], acc1[m][nt], 0, 0, 0);
                    acc1[m][nt] = __builtin_amdgcn_mfma_f32_16x16x32_f16(al, Wh[nt][ks], acc1[m][nt], 0, 0, 0);
                    acc1[m][nt] = __builtin_amdgcn_mfma_f32_16x16x32_f16(ah, Wh[nt][ks], acc1[m][nt], 0, 0, 0);
                }
            }
        }
        // GN1 (64-ch groups = wave pair {w, w^1}) partials
        float ps[3][4], ps2[3][4];
        #pragma unroll
        for (int m = 0; m < 3; m++) {
            #pragma unroll
            for (int r = 0; r < 4; r++) {
                float v0 = acc1[m][0][r] + bi1A[half][0], v1 = acc1[m][1][r] + bi1A[half][1];
                float s = v0 + v1, s2 = v0 * v0 + v1 * v1;
                #pragma unroll
                for (int mk = 1; mk <= 8; mk <<= 1) { s += __shfl_xor(s, mk); s2 += __shfl_xor(s2, mk); }
                ps[m][r] = s; ps2[m][r] = s2;
            }
        }
        if (lr == 0) {
            #pragma unroll
            for (int m = 0; m < 3; m++)
                #pragma unroll
                for (int r = 0; r < 4; r++)
                    partS[w * 48 + m * 16 + lg * 4 + r] = make_float2(ps[m][r], ps2[m][r]);
        }
        __syncthreads();
        #pragma unroll
        for (int m = 0; m < 3; m++) {
            #pragma unroll
            for (int r = 0; r < 4; r++) {
                float2 q = partS[(w ^ 1) * 48 + m * 16 + lg * 4 + r];
                float st = ps[m][r] + q.x, s2t = ps2[m][r] + q.y;
                float mu = st * (1.f / 64.f);
                float rs = rsqrtf(s2t * (1.f / 64.f) - mu * mu + EPS);
                int row = m * 16 + lg * 4 + r;
                #pragma unroll
                for (int nt = 0; nt < 2; nt++) {
                    float v = acc1[m][nt][r] + bi1A[half][nt];
                    float hv = fmaxf(fmaf((v - mu) * rs, gg1A[half][nt], bb1A[half][nt]), 0.f);
                    _Float16 h16 = (_Float16)hv;
                    int ii = sidx(row, w * 32 + nt * 16 + lr);
                    Hh[ii] = __builtin_bit_cast(ushort_t, h16);
                    Hl[ii] = __builtin_bit_cast(ushort_t, (_Float16)(hv - (float)h16));
                }
            }
        }
        __syncthreads();

        // issue half-1 weight loads here: they complete under GEMM2's MFMAs
        if (prefetch_next) {
            #pragma unroll
            for (int nt = 0; nt < 2; nt++) {
                int n = 128 + cA + nt * 16;
                #pragma unroll
                for (int ks = 0; ks < 4; ks++) {
                    bh1[nt][ks]  = *(const f16x8*)(w1h + n * 128 + ks * 32 + lg * 8);
                    bl1[nt][ks]  = *(const f16x8*)(w1l + n * 128 + ks * 32 + lg * 8);
                    c2h1[nt][ks] = *(const f16x8*)(w2h + (cA + nt * 16) * 256 + 128 + ks * 32 + lg * 8);
                    c2l1[nt][ks] = *(const f16x8*)(w2l + (cA + nt * 16) * 256 + 128 + ks * 32 + lg * 8);
                }
            }
        }

        // GEMM2 partial: K-slice = this half's 128 h1 channels
        #pragma unroll
        for (int m = 0; m < 3; m++) {
            #pragma unroll
            for (int ks = 0; ks < 4; ks++) {
                f16x8 ah = *(const f16x8*)&Hh[sidx(m * 16 + lr, ks * 32 + lg * 8)];
                f16x8 al = *(const f16x8*)&Hl[sidx(m * 16 + lr, ks * 32 + lg * 8)];
                #pragma unroll
                for (int nt = 0; nt < 2; nt++) {
                    acc2[m][nt] = __builtin_amdgcn_mfma_f32_16x16x32_f16(ah, Vl[nt][ks], acc2[m][nt], 0, 0, 0);
                    acc2[m][nt] = __builtin_amdgcn_mfma_f32_16x16x32_f16(al, Vh[nt][ks], acc2[m][nt], 0, 0, 0);
                    acc2[m][nt] = __builtin_amdgcn_mfma_f32_16x16x32_f16(ah, Vh[nt][ks], acc2[m][nt], 0, 0, 0);
                }
            }
        }
        __syncthreads();   // H region free; (half1: Ah token reads long done)
    };

    do_half(bh0, bl0, c2h0, c2l0, 0, true);
    do_half(bh1, bl1, c2h1, c2l1, 1, false);

    // ---- fused epilogue: GN2 (wave-local) + in_norm (wave-local) + PE, all in-register ----
    {
        float hv[3][4][2];
        #pragma unroll
        for (int m = 0; m < 3; m++) {
            #pragma unroll
            for (int r = 0; r < 4; r++) {
                float v0 = acc2[m][0][r] + b2v[0], v1 = acc2[m][1][r] + b2v[1];
                float s = v0 + v1, s2 = v0 * v0 + v1 * v1;
                #pragma unroll
                for (int mk = 1; mk <= 8; mk <<= 1) { s += __shfl_xor(s, mk); s2 += __shfl_xor(s2, mk); }
                float mu = s * (1.f / 32.f);
                float rs = rsqrtf(s2 * (1.f / 32.f) - mu * mu + EPS);
                hv[m][r][0] = fmaxf(fmaf((v0 - mu) * rs, g2v[0], be2v[0]), 0.f);
                hv[m][r][1] = fmaxf(fmaf((v1 - mu) * rs, g2v[1], be2v[1]), 0.f);
            }
        }
        // in_norm partials: group = 8 channels x 24 tokens of one pixel, entirely in-wave
        float s0[2] = {0.f, 0.f}, s02[2] = {0.f, 0.f};
        float s1[2] = {0.f, 0.f}, s12[2] = {0.f, 0.f};
        #pragma unroll
        for (int m = 0; m < 3; m++) {
            #pragma unroll
            for (int r = 0; r < 4; r++) {
                int row = m * 16 + lg * 4 + r;
                #pragma unroll
                for (int nt = 0; nt < 2; nt++) {
                    float v = hv[m][r][nt];
                    if (row >= 24) { s1[nt] += v; s12[nt] += v * v; }
                    else           { s0[nt] += v; s02[nt] += v * v; }
                }
            }
        }
        // reduce over lane bits 0,1,2 (channel-in-group) and 4,5 (lg): masks 1,2,4,16,32
        #pragma unroll
        for (int nt = 0; nt < 2; nt++) {
            #pragma unroll
            for (int mk = 0; mk < 5; mk++) {
                int msk = (mk < 3) ? (1 << mk) : (2 << mk);   // 1,2,4,16,32
                s0[nt] += __shfl_xor(s0[nt], msk);  s02[nt] += __shfl_xor(s02[nt], msk);
                s1[nt] += __shfl_xor(s1[nt], msk);  s12[nt] += __shfl_xor(s12[nt], msk);
            }
        }
        float mu0[2], rs0[2], mu1[2], rs1[2];
        #pragma unroll
        for (int nt = 0; nt < 2; nt++) {
            mu0[nt] = s0[nt] * (1.f / 192.f);
            rs0[nt] = rsqrtf(s02[nt] * (1.f / 192.f) - mu0[nt] * mu0[nt] + EPS);
            mu1[nt] = s1[nt] * (1.f / 192.f);
            rs1[nt] = rsqrtf(s12[nt] * (1.f / 192.f) - mu1[nt] * mu1[nt] + EPS);
        }
        // apply + PE, write xs2 hi/lo into A region
        #pragma unroll
        for (int m = 0; m < 3; m++) {
            #pragma unroll
            for (int r = 0; r < 4; r++) {
                int row = m * 16 + lg * 4 + r;
                int p1 = row >= 24;
                int t = row - (p1 ? 24 : 0);
                float pe = peS[t][lr & 7];
                #pragma unroll
                for (int nt = 0; nt < 2; nt++) {
                    float mu = p1 ? mu1[nt] : mu0[nt];
                    float rs = p1 ? rs1[nt] : rs0[nt];
                    float v = fmaf((hv[m][r][nt] - mu) * rs, giV[nt], biV[nt]) + pe;
                    _Float16 h16 = (_Float16)v;
                    int ii = sidx(row, w * 32 + nt * 16 + lr);
                    Ah[ii] = __builtin_bit_cast(ushort_t, h16);
                    Al[ii] = __builtin_bit_cast(ushort_t, (_Float16)(v - (float)h16));
                }
            }
        }
    }

    // ---- scores prefetch (issue before barrier; complete at barrier) ----
    f16x8 qh[4], ql[4];
    float qb = 0.f;
    if (w < 3) {
        #pragma unroll
        for (int ks = 0; ks < 4; ks++) {
            qh[ks] = *(const f16x8*)(qkBh + ((ks * 4 + lg) * 16 + lr) * 8);
            ql[ks] = *(const f16x8*)(qkBl + ((ks * 4 + lg) * 16 + lr) * 8);
        }
        qb = qb2G[lr];
    }
    __syncthreads();

    // ---- scores via split-fp16 MFMA (waves 0..2 = 3 m-tiles) ----
    if (w < 3) {
        const int m = w;
        f32x4 sacc = f32x4{0.f, 0.f, 0.f, 0.f};
        #pragma unroll
        for (int ks = 0; ks < 4; ks++) {
            f16x8 ah = *(const f16x8*)&Ah[sidx(m * 16 + lr, ks * 32 + lg * 8)];
            f16x8 al = *(const f16x8*)&Al[sidx(m * 16 + lr, ks * 32 + lg * 8)];
            sacc = __builtin_amdgcn_mfma_f32_16x16x32_f16(ah, ql[ks], sacc, 0, 0, 0);
            sacc = __builtin_amdgcn_mfma_f32_16x16x32_f16(al, qh[ks], sacc, 0, 0, 0);
            sacc = __builtin_amdgcn_mfma_f32_16x16x32_f16(ah, qh[ks], sacc, 0, 0, 0);
        }
        #pragma unroll
        for (int r = 0; r < 4; r++) {
            int row = m * 16 + lg * 4 + r;
            int p = row >= 24 ? 1 : 0;
            int t = row - p * 24;
            scP[(p * 16 + lr) * 24 + t] = sacc[r] + qb;
        }
    }
    __syncthreads();

    // ---- softmax: wave w -> pixel w>>1, heads (w&1)*8 + l>>3 ----
    {
        const int p = w >> 1;
        int h = (w & 1) * 8 + (l >> 3), j = l & 7;
        float* sp = scP + (p * 16 + h) * 24;
        float mx = -1e30f;
        #pragma unroll
        for (int k = 0; k < 3; k++) mx = fmaxf(mx, sp[j + 8 * k]);
        mx = fmaxf(mx, __shfl_xor(mx, 1));
        mx = fmaxf(mx, __shfl_xor(mx, 2));
        mx = fmaxf(mx, __shfl_xor(mx, 4));
        float ev[3], sum = 0.f;
        #pragma unroll
        for (int k = 0; k < 3; k++) { ev[k] = __expf(sp[j + 8 * k] - mx); sum += ev[k]; }
        sum += __shfl_xor(sum, 1);
        sum += __shfl_xor(sum, 2);
        sum += __shfl_xor(sum, 4);
        float inv = 1.f / sum;
        #pragma unroll
        for (int k = 0; k < 3; k++) sp[j + 8 * k] = ev[k] * inv;
    }

    // ---- o = a . v (wave-local heads) ----
    {
        const int p = w >> 1;
        int ch = (w & 1) * 64 + l;
        int h = ch >> 3;
        const float* sp = scP + (p * 16 + h) * 24;
        float s = 0.f;
        #pragma unroll
        for (int t = 0; t < 24; t++) {
            int ii = sidx(p * 24 + t, ch);
            float v = (float)__builtin_bit_cast(_Float16, Ah[ii]) +
                      (float)__builtin_bit_cast(_Float16, Al[ii]);
            s = fmaf(sp[t], v, s);
        }
        ovP[p * 128 + ch] = s;
    }
    __syncthreads();

    // ---- MLP layer 1 (128->256) + GN(4/64) + ReLU ----
    {
        const int o = tid;
        const float* wr = w_m0 + o * 128;
        float acc[2] = {0.f, 0.f};
        for (int c0 = 0; c0 < 128; c0 += 4) {
            float4 w4 = *(const float4*)(wr + c0);
            #pragma unroll
            for (int pp = 0; pp < 2; pp++) {
                float4 x4 = *(const float4*)(ovP + pp * 128 + c0);
                acc[pp] = fmaf(w4.x, x4.x, acc[pp]); acc[pp] = fmaf(w4.y, x4.y, acc[pp]);
                acc[pp] = fmaf(w4.z, x4.z, acc[pp]); acc[pp] = fmaf(w4.w, x4.w, acc[pp]);
            }
        }
        float bi = b_m0[o], gg = g_m0[o], bb = be_m0[o];
        #pragma unroll
        for (int pp = 0; pp < 2; pp++) {
            float v = acc[pp] + bi;
            float s = v, s2 = v * v;
            #pragma unroll
            for (int mk = 1; mk <= 32; mk <<= 1) { s += __shfl_xor(s, mk); s2 += __shfl_xor(s2, mk); }
            float mu = s * (1.f / 64.f);
            float rs = rsqrtf(s2 * (1.f / 64.f) - mu * mu + EPS);
            mmP[pp * 256 + o] = fmaxf(fmaf((v - mu) * rs, gg, bb), 0.f);
        }
    }
    __syncthreads();

    // ---- MLP layer 2 (256->128) + GN(4/32) + ReLU + out_norm GN(16/8) ----
    {
        const int o = tid & 127, pp = tid >> 7;
        const float* wr = w_m1 + o * 256;
        float acc = 0.f;
        for (int c0 = 0; c0 < 256; c0 += 4) {
            float4 w4 = *(const float4*)(wr + c0);
            float4 x4 = *(const float4*)(mmP + pp * 256 + c0);
            acc = fmaf(w4.x, x4.x, acc); acc = fmaf(w4.y, x4.y, acc);
            acc = fmaf(w4.z, x4.z, acc); acc = fmaf(w4.w, x4.w, acc);
        }
        float v = acc + b_m1[o];
        float s = v, s2 = v * v;
        #pragma unroll
        for (int mk = 1; mk <= 16; mk <<= 1) { s += __shfl_xor(s, mk); s2 += __shfl_xor(s2, mk); }
        float mu = s * (1.f / 32.f);
        float rs = rsqrtf(s2 * (1.f / 32.f) - mu * mu + EPS);
        float v2 = fmaxf(fmaf((v - mu) * rs, g_m1[o], be_m1[o]), 0.f);
        float t1 = v2, t2 = v2 * v2;
        #pragma unroll
        for (int mk = 1; mk <= 4; mk <<= 1) { t1 += __shfl_xor(t1, mk); t2 += __shfl_xor(t2, mk); }
        float mu2 = t1 * (1.f / 8.f);
        float rs2 = rsqrtf(t2 * (1.f / 8.f) - mu2 * mu2 + EPS);
        ysP[pp * 128 + o] = fmaf((v2 - mu2) * rs2, g_out[o], b_out[o]);
    }
    __syncthreads();

    // ---- store (float2 across the 2 pixels) ----
    if (tid < 128) {
        float2 y2;
        y2.x = ysP[0 * 128 + tid];
        y2.y = ysP[1 * 128 + tid];
        *(float2*)(out + ((size_t)(b * 128 + tid)) * HWp + pixbase) = y2;
    }
}

extern "C" void kernel_launch(void* const* d_in, const int* in_sizes, int n_in,
                              void* d_out, int out_size, void* d_ws, size_t ws_size,
                              hipStream_t stream) {
    const float* x        = (const float*)d_in[0];
    const int*   bpos     = (const int*)  d_in[1];
    const float* w_in0    = (const float*)d_in[2];
    const float* b_in0    = (const float*)d_in[3];
    const float* g_in0    = (const float*)d_in[4];
    const float* be_in0   = (const float*)d_in[5];
    const float* w_in1    = (const float*)d_in[6];
    const float* b_in1    = (const float*)d_in[7];
    const float* g_in1    = (const float*)d_in[8];
    const float* be_in1   = (const float*)d_in[9];
    const float* g_innorm = (const float*)d_in[10];
    const float* b_innorm = (const float*)d_in[11];
    const float* Qm       = (const float*)d_in[12];
    const float* w_k      = (const float*)d_in[13];
    const float* b_k      = (const float*)d_in[14];
    const float* w_m0     = (const float*)d_in[15];
    const float* b_m0     = (const float*)d_in[16];
    const float* g_m0     = (const float*)d_in[17];
    const float* be_m0    = (const float*)d_in[18];
    const float* w_m1     = (const float*)d_in[19];
    const float* b_m1     = (const float*)d_in[20];
    const float* g_m1     = (const float*)d_in[21];
    const float* be_m1    = (const float*)d_in[22];
    const float* g_out    = (const float*)d_in[23];
    const float* b_out    = (const float*)d_in[24];

    _Float16* w1h  = (_Float16*)d_ws;
    _Float16* w1l  = w1h + 32768;
    _Float16* w2h  = w1l + 32768;
    _Float16* w2l  = w2h + 32768;
    _Float16* qkBh = (_Float16*)((char*)d_ws + 262144);
    _Float16* qkBl = qkBh + 2048;
    float*    qb2G = (float*)((char*)d_ws + 270336);
    float*    peG  = (float*)((char*)d_ws + 270400);

    hipLaunchKernelGGL(ltae_prep, dim3(268), dim3(256), 0, stream,
                       w_in0, w_in1, Qm, w_k, b_k, bpos,
                       w1h, w1l, w2h, w2l, qkBh, qkBl, qb2G, peG);

    hipLaunchKernelGGL(ltae_main, dim3(4608), dim3(256), 0, stream,
                       x,
                       b_in0, g_in0, be_in0,
                       b_in1, g_in1, be_in1,
                       g_innorm, b_innorm,
                       w_m0, b_m0, g_m0, be_m0,
                       w_m1, b_m1, g_m1, be_m1,
                       g_out, b_out,
                       w1h, w1l, w2h, w2l, qkBh, qkBl, qb2G, peG,
                       (float*)d_out);
}

// Round 10
// 466.537 us; speedup vs baseline: 1.3706x; 1.0949x over previous
//
#include <hip/hip_runtime.h>
#include <math.h>

typedef _Float16 f16x8 __attribute__((ext_vector_type(8)));
typedef float f32x4 __attribute__((ext_vector_type(4)));
typedef unsigned short ushort_t;

constexpr int HWp = 2304;
constexpr float EPS = 1e-5f;

// swizzled ushort index, 256B rows (128 fp16 cols): byte = row*256 + ((c*2)^((row&7)<<4))
__device__ __forceinline__ int sidx(int row, int c) {
    return ((row << 8) + ((c << 1) ^ ((row & 7) << 4))) >> 1;
}

// ---------------- prep: weights -> split fp16 (hi/lo), fold Q+scale, PE table ----------------
__global__ void ltae_prep(const float* __restrict__ w_in0, const float* __restrict__ w_in1,
                          const float* __restrict__ Qm, const float* __restrict__ w_k,
                          const float* __restrict__ b_k, const int* __restrict__ bpos,
                          _Float16* __restrict__ w1h, _Float16* __restrict__ w1l,
                          _Float16* __restrict__ w2h, _Float16* __restrict__ w2l,
                          _Float16* __restrict__ qkBh, _Float16* __restrict__ qkBl,
                          float* __restrict__ qb2G, float* __restrict__ peG) {
    int i = blockIdx.x * 256 + threadIdx.x;
    if (i < 32768) {
        float v = w_in0[i];
        _Float16 h = (_Float16)v;
        w1h[i] = h; w1l[i] = (_Float16)(v - (float)h);
    } else if (i < 65536) {
        int j = i - 32768;
        float v = w_in1[j];
        _Float16 h = (_Float16)v;
        w2h[j] = h; w2l[j] = (_Float16)(v - (float)h);
    } else if (i < 67584) {
        int j = i - 65536; int h = j >> 7, k = j & 127;
        float s = 0.f;
        #pragma unroll
        for (int dk = 0; dk < 4; dk++) s = fmaf(Qm[h * 4 + dk], w_k[(h * 4 + dk) * 128 + k], s);
        s *= 0.5f;
        _Float16 hi = (_Float16)s;
        int ks = k >> 5, lg = (k >> 3) & 3, jj = k & 7;
        int pos = ((ks * 4 + lg) * 16 + h) * 8 + jj;
        qkBh[pos] = hi; qkBl[pos] = (_Float16)(s - (float)hi);
    } else if (i < 67600) {
        int h = i - 67584;
        float s = 0.f;
        #pragma unroll
        for (int dk = 0; dk < 4; dk++) s = fmaf(Qm[h * 4 + dk], b_k[h * 4 + dk], s);
        qb2G[h] = 0.5f * s;
    } else if (i < 68368) {
        int j = i - 67600;
        int bb = j / 192, r = j - bb * 192;
        int t = r >> 3, d = r & 7;
        const float dens[4] = {1.0f, 5.623413251903491f, 31.622776601683793f, 177.82794100389228f};
        float ang = (float)bpos[bb * 24 + t] / dens[d >> 1];
        peG[j] = (d & 1) ? cosf(ang) : sinf(ang);
    }
}

// ---------------- main: 2 pixels per 4-wave block, 3 blocks/CU ----------------
__global__ __launch_bounds__(256, 3) void ltae_main(
    const float* __restrict__ x,
    const float* __restrict__ b_in0, const float* __restrict__ g_in0, const float* __restrict__ be_in0,
    const float* __restrict__ b_in1, const float* __restrict__ g_in1, const float* __restrict__ be_in1,
    const float* __restrict__ g_innorm, const float* __restrict__ b_innorm,
    const float* __restrict__ w_m0, const float* __restrict__ b_m0,
    const float* __restrict__ g_m0, const float* __restrict__ be_m0,
    const float* __restrict__ w_m1, const float* __restrict__ b_m1,
    const float* __restrict__ g_m1, const float* __restrict__ be_m1,
    const float* __restrict__ g_out, const float* __restrict__ b_out,
    const _Float16* __restrict__ w1h, const _Float16* __restrict__ w1l,
    const _Float16* __restrict__ w2h, const _Float16* __restrict__ w2l,
    const _Float16* __restrict__ qkBh, const _Float16* __restrict__ qkBl,
    const float* __restrict__ qb2G, const float* __restrict__ peG,
    float* __restrict__ out)
{
    __shared__ __align__(16) ushort_t Ah[48 * 128], Al[48 * 128];  // tokens, later xs2 hi/lo
    __shared__ __align__(16) ushort_t Hh[48 * 128], Hl[48 * 128];  // h1 half-tile hi/lo
    __shared__ float peS[24][8];
    __shared__ float2 partS[192];     // GN1 cross-wave partials

    float* scP = (float*)Hh;          // [2][16][24] overlays H after GEMMs
    float* ovP = scP + 768;           // [2][128]
    float* mmP = ovP + 256;           // [2][256]
    float* ysP = ovP;

    const int tid = threadIdx.x;
    const int bid = blockIdx.x;
    const int sb  = (bid & 7) * 576 + (bid >> 3);   // bijective XCD swizzle (4608 = 8*576)
    const int b   = sb / 1152;
    const int pixbase = (sb - b * 1152) * 2;
    const int w  = tid >> 6;
    const int l  = tid & 63;
    const int lr = l & 15;
    const int lg = l >> 4;

    // ---- hoisted per-thread scalars (small; complete under gather) ----
    const int cA = w * 32 + lr;
    const int cB = cA + 16;
    float bi1A[2][2], gg1A[2][2], bb1A[2][2];
    #pragma unroll
    for (int nt = 0; nt < 2; nt++) {
        int n = cA + nt * 16;
        bi1A[0][nt] = b_in0[n];       gg1A[0][nt] = g_in0[n];       bb1A[0][nt] = be_in0[n];
        bi1A[1][nt] = b_in0[n + 128]; gg1A[1][nt] = g_in0[n + 128]; bb1A[1][nt] = be_in0[n + 128];
    }
    float b2v[2]  = {b_in1[cA], b_in1[cB]};
    float g2v[2]  = {g_in1[cA], g_in1[cB]};
    float be2v[2] = {be_in1[cA], be_in1[cB]};
    float giV[2]  = {g_innorm[cA], g_innorm[cB]};
    float biV[2]  = {b_innorm[cA], b_innorm[cB]};

    // ---- gather tokens -> Ah/Al (split fp16, swizzled) + PE cache ----
    if (tid < 192) peS[tid >> 3][tid & 7] = peG[b * 192 + tid];
    for (int i = tid; i < 24 * 128; i += 256) {
        int t = i >> 7, c = i & 127;
        const float* gp = x + ((size_t)((b * 24 + t) * 128 + c)) * HWp + pixbase;
        float2 v = *(const float2*)gp;
        _Float16 h0 = (_Float16)v.x;
        _Float16 h1 = (_Float16)v.y;
        int i0 = sidx(t, c), i1 = sidx(24 + t, c);
        Ah[i0] = __builtin_bit_cast(ushort_t, h0);
        Al[i0] = __builtin_bit_cast(ushort_t, (_Float16)(v.x - (float)h0));
        Ah[i1] = __builtin_bit_cast(ushort_t, h1);
        Al[i1] = __builtin_bit_cast(ushort_t, (_Float16)(v.y - (float)h1));
    }
    __syncthreads();

    f32x4 acc2[3][2];
    #pragma unroll
    for (int m = 0; m < 3; m++)
        #pragma unroll
        for (int nt = 0; nt < 2; nt++) acc2[m][nt] = f32x4{0.f, 0.f, 0.f, 0.f};

    #pragma unroll 1
    for (int half = 0; half < 2; half++) {
        // GEMM1 weights at point of use (R4 style; no lambda, no cross-half prefetch)
        f16x8 bh[2][4], bl[2][4];
        #pragma unroll
        for (int nt = 0; nt < 2; nt++) {
            int n = half * 128 + cA + nt * 16;
            #pragma unroll
            for (int ks = 0; ks < 4; ks++) {
                bh[nt][ks] = *(const f16x8*)(w1h + n * 128 + ks * 32 + lg * 8);
                bl[nt][ks] = *(const f16x8*)(w1l + n * 128 + ks * 32 + lg * 8);
            }
        }
        f32x4 acc1[3][2];
        #pragma unroll
        for (int m = 0; m < 3; m++)
            #pragma unroll
            for (int nt = 0; nt < 2; nt++) acc1[m][nt] = f32x4{0.f, 0.f, 0.f, 0.f};
        #pragma unroll
        for (int m = 0; m < 3; m++) {
            #pragma unroll
            for (int ks = 0; ks < 4; ks++) {
                f16x8 ah = *(const f16x8*)&Ah[sidx(m * 16 + lr, ks * 32 + lg * 8)];
                f16x8 al = *(const f16x8*)&Al[sidx(m * 16 + lr, ks * 32 + lg * 8)];
                #pragma unroll
                for (int nt = 0; nt < 2; nt++) {
                    acc1[m][nt] = __builtin_amdgcn_mfma_f32_16x16x32_f16(ah, bl[nt][ks], acc1[m][nt], 0, 0, 0);
                    acc1[m][nt] = __builtin_amdgcn_mfma_f32_16x16x32_f16(al, bh[nt][ks], acc1[m][nt], 0, 0, 0);
                    acc1[m][nt] = __builtin_amdgcn_mfma_f32_16x16x32_f16(ah, bh[nt][ks], acc1[m][nt], 0, 0, 0);
                }
            }
        }
        // GN1 (64-ch groups = wave pair {w, w^1}) partials
        float ps[3][4], ps2[3][4];
        #pragma unroll
        for (int m = 0; m < 3; m++) {
            #pragma unroll
            for (int r = 0; r < 4; r++) {
                float v0 = acc1[m][0][r] + bi1A[half][0], v1 = acc1[m][1][r] + bi1A[half][1];
                float s = v0 + v1, s2 = v0 * v0 + v1 * v1;
                #pragma unroll
                for (int mk = 1; mk <= 8; mk <<= 1) { s += __shfl_xor(s, mk); s2 += __shfl_xor(s2, mk); }
                ps[m][r] = s; ps2[m][r] = s2;
            }
        }
        if (lr == 0) {
            #pragma unroll
            for (int m = 0; m < 3; m++)
                #pragma unroll
                for (int r = 0; r < 4; r++)
                    partS[w * 48 + m * 16 + lg * 4 + r] = make_float2(ps[m][r], ps2[m][r]);
        }
        __syncthreads();
        #pragma unroll
        for (int m = 0; m < 3; m++) {
            #pragma unroll
            for (int r = 0; r < 4; r++) {
                float2 q = partS[(w ^ 1) * 48 + m * 16 + lg * 4 + r];
                float st = ps[m][r] + q.x, s2t = ps2[m][r] + q.y;
                float mu = st * (1.f / 64.f);
                float rs = rsqrtf(s2t * (1.f / 64.f) - mu * mu + EPS);
                int row = m * 16 + lg * 4 + r;
                #pragma unroll
                for (int nt = 0; nt < 2; nt++) {
                    float v = acc1[m][nt][r] + bi1A[half][nt];
                    float hv = fmaxf(fmaf((v - mu) * rs, gg1A[half][nt], bb1A[half][nt]), 0.f);
                    _Float16 h16 = (_Float16)hv;
                    int ii = sidx(row, w * 32 + nt * 16 + lr);
                    Hh[ii] = __builtin_bit_cast(ushort_t, h16);
                    Hl[ii] = __builtin_bit_cast(ushort_t, (_Float16)(hv - (float)h16));
                }
            }
        }
        __syncthreads();

        // GEMM2 partial: weights at point of use; loads overlap the H ds_reads
        f16x8 b2h[2][4], b2l[2][4];
        #pragma unroll
        for (int nt = 0; nt < 2; nt++) {
            int n = cA + nt * 16;
            #pragma unroll
            for (int ks = 0; ks < 4; ks++) {
                b2h[nt][ks] = *(const f16x8*)(w2h + n * 256 + half * 128 + ks * 32 + lg * 8);
                b2l[nt][ks] = *(const f16x8*)(w2l + n * 256 + half * 128 + ks * 32 + lg * 8);
            }
        }
        #pragma unroll
        for (int m = 0; m < 3; m++) {
            #pragma unroll
            for (int ks = 0; ks < 4; ks++) {
                f16x8 ah = *(const f16x8*)&Hh[sidx(m * 16 + lr, ks * 32 + lg * 8)];
                f16x8 al = *(const f16x8*)&Hl[sidx(m * 16 + lr, ks * 32 + lg * 8)];
                #pragma unroll
                for (int nt = 0; nt < 2; nt++) {
                    acc2[m][nt] = __builtin_amdgcn_mfma_f32_16x16x32_f16(ah, b2l[nt][ks], acc2[m][nt], 0, 0, 0);
                    acc2[m][nt] = __builtin_amdgcn_mfma_f32_16x16x32_f16(al, b2h[nt][ks], acc2[m][nt], 0, 0, 0);
                    acc2[m][nt] = __builtin_amdgcn_mfma_f32_16x16x32_f16(ah, b2h[nt][ks], acc2[m][nt], 0, 0, 0);
                }
            }
        }
        __syncthreads();   // H region free for next half
    }

    // ---- fused epilogue: GN2 (wave-local) + in_norm (wave-local) + PE, all in-register ----
    {
        float hv[3][4][2];
        #pragma unroll
        for (int m = 0; m < 3; m++) {
            #pragma unroll
            for (int r = 0; r < 4; r++) {
                float v0 = acc2[m][0][r] + b2v[0], v1 = acc2[m][1][r] + b2v[1];
                float s = v0 + v1, s2 = v0 * v0 + v1 * v1;
                #pragma unroll
                for (int mk = 1; mk <= 8; mk <<= 1) { s += __shfl_xor(s, mk); s2 += __shfl_xor(s2, mk); }
                float mu = s * (1.f / 32.f);
                float rs = rsqrtf(s2 * (1.f / 32.f) - mu * mu + EPS);
                hv[m][r][0] = fmaxf(fmaf((v0 - mu) * rs, g2v[0], be2v[0]), 0.f);
                hv[m][r][1] = fmaxf(fmaf((v1 - mu) * rs, g2v[1], be2v[1]), 0.f);
            }
        }
        // in_norm partials: group = 8 channels x 24 tokens of one pixel, entirely in-wave
        float s0[2] = {0.f, 0.f}, s02[2] = {0.f, 0.f};
        float s1[2] = {0.f, 0.f}, s12[2] = {0.f, 0.f};
        #pragma unroll
        for (int m = 0; m < 3; m++) {
            #pragma unroll
            for (int r = 0; r < 4; r++) {
                int row = m * 16 + lg * 4 + r;
                #pragma unroll
                for (int nt = 0; nt < 2; nt++) {
                    float v = hv[m][r][nt];
                    if (row >= 24) { s1[nt] += v; s12[nt] += v * v; }
                    else           { s0[nt] += v; s02[nt] += v * v; }
                }
            }
        }
        // reduce over lane bits 0,1,2 (channel-in-group) and 4,5 (lg): masks 1,2,4,16,32
        #pragma unroll
        for (int nt = 0; nt < 2; nt++) {
            #pragma unroll
            for (int mk = 0; mk < 5; mk++) {
                int msk = (mk < 3) ? (1 << mk) : (2 << mk);   // 1,2,4,16,32
                s0[nt] += __shfl_xor(s0[nt], msk);  s02[nt] += __shfl_xor(s02[nt], msk);
                s1[nt] += __shfl_xor(s1[nt], msk);  s12[nt] += __shfl_xor(s12[nt], msk);
            }
        }
        float mu0[2], rs0[2], mu1[2], rs1[2];
        #pragma unroll
        for (int nt = 0; nt < 2; nt++) {
            mu0[nt] = s0[nt] * (1.f / 192.f);
            rs0[nt] = rsqrtf(s02[nt] * (1.f / 192.f) - mu0[nt] * mu0[nt] + EPS);
            mu1[nt] = s1[nt] * (1.f / 192.f);
            rs1[nt] = rsqrtf(s12[nt] * (1.f / 192.f) - mu1[nt] * mu1[nt] + EPS);
        }
        // apply + PE, write xs2 hi/lo into A region
        #pragma unroll
        for (int m = 0; m < 3; m++) {
            #pragma unroll
            for (int r = 0; r < 4; r++) {
                int row = m * 16 + lg * 4 + r;
                int p1 = row >= 24;
                int t = row - (p1 ? 24 : 0);
                float pe = peS[t][lr & 7];
                #pragma unroll
                for (int nt = 0; nt < 2; nt++) {
                    float mu = p1 ? mu1[nt] : mu0[nt];
                    float rs = p1 ? rs1[nt] : rs0[nt];
                    float v = fmaf((hv[m][r][nt] - mu) * rs, giV[nt], biV[nt]) + pe;
                    _Float16 h16 = (_Float16)v;
                    int ii = sidx(row, w * 32 + nt * 16 + lr);
                    Ah[ii] = __builtin_bit_cast(ushort_t, h16);
                    Al[ii] = __builtin_bit_cast(ushort_t, (_Float16)(v - (float)h16));
                }
            }
        }
    }

    // ---- scores prefetch (issue before barrier; complete at barrier) ----
    f16x8 qh[4], ql[4];
    float qb = 0.f;
    if (w < 3) {
        #pragma unroll
        for (int ks = 0; ks < 4; ks++) {
            qh[ks] = *(const f16x8*)(qkBh + ((ks * 4 + lg) * 16 + lr) * 8);
            ql[ks] = *(const f16x8*)(qkBl + ((ks * 4 + lg) * 16 + lr) * 8);
        }
        qb = qb2G[lr];
    }
    __syncthreads();

    // ---- scores via split-fp16 MFMA (waves 0..2 = 3 m-tiles) ----
    if (w < 3) {
        const int m = w;
        f32x4 sacc = f32x4{0.f, 0.f, 0.f, 0.f};
        #pragma unroll
        for (int ks = 0; ks < 4; ks++) {
            f16x8 ah = *(const f16x8*)&Ah[sidx(m * 16 + lr, ks * 32 + lg * 8)];
            f16x8 al = *(const f16x8*)&Al[sidx(m * 16 + lr, ks * 32 + lg * 8)];
            sacc = __builtin_amdgcn_mfma_f32_16x16x32_f16(ah, ql[ks], sacc, 0, 0, 0);
            sacc = __builtin_amdgcn_mfma_f32_16x16x32_f16(al, qh[ks], sacc, 0, 0, 0);
            sacc = __builtin_amdgcn_mfma_f32_16x16x32_f16(ah, qh[ks], sacc, 0, 0, 0);
        }
        #pragma unroll
        for (int r = 0; r < 4; r++) {
            int row = m * 16 + lg * 4 + r;
            int p = row >= 24 ? 1 : 0;
            int t = row - p * 24;
            scP[(p * 16 + lr) * 24 + t] = sacc[r] + qb;
        }
    }
    __syncthreads();

    // ---- softmax: wave w -> pixel w>>1, heads (w&1)*8 + l>>3 ----
    {
        const int p = w >> 1;
        int h = (w & 1) * 8 + (l >> 3), j = l & 7;
        float* sp = scP + (p * 16 + h) * 24;
        float mx = -1e30f;
        #pragma unroll
        for (int k = 0; k < 3; k++) mx = fmaxf(mx, sp[j + 8 * k]);
        mx = fmaxf(mx, __shfl_xor(mx, 1));
        mx = fmaxf(mx, __shfl_xor(mx, 2));
        mx = fmaxf(mx, __shfl_xor(mx, 4));
        float ev[3], sum = 0.f;
        #pragma unroll
        for (int k = 0; k < 3; k++) { ev[k] = __expf(sp[j + 8 * k] - mx); sum += ev[k]; }
        sum += __shfl_xor(sum, 1);
        sum += __shfl_xor(sum, 2);
        sum += __shfl_xor(sum, 4);
        float inv = 1.f / sum;
        #pragma unroll
        for (int k = 0; k < 3; k++) sp[j + 8 * k] = ev[k] * inv;
    }

    // ---- o = a . v (wave-local heads) ----
    {
        const int p = w >> 1;
        int ch = (w & 1) * 64 + l;
        int h = ch >> 3;
        const float* sp = scP + (p * 16 + h) * 24;
        float s = 0.f;
        #pragma unroll
        for (int t = 0; t < 24; t++) {
            int ii = sidx(p * 24 + t, ch);
            float v = (float)__builtin_bit_cast(_Float16, Ah[ii]) +
                      (float)__builtin_bit_cast(_Float16, Al[ii]);
            s = fmaf(sp[t], v, s);
        }
        ovP[p * 128 + ch] = s;
    }
    __syncthreads();

    // ---- MLP layer 1 (128->256) + GN(4/64) + ReLU ----
    {
        const int o = tid;
        const float* wr = w_m0 + o * 128;
        float acc[2] = {0.f, 0.f};
        for (int c0 = 0; c0 < 128; c0 += 4) {
            float4 w4 = *(const float4*)(wr + c0);
            #pragma unroll
            for (int pp = 0; pp < 2; pp++) {
                float4 x4 = *(const float4*)(ovP + pp * 128 + c0);
                acc[pp] = fmaf(w4.x, x4.x, acc[pp]); acc[pp] = fmaf(w4.y, x4.y, acc[pp]);
                acc[pp] = fmaf(w4.z, x4.z, acc[pp]); acc[pp] = fmaf(w4.w, x4.w, acc[pp]);
            }
        }
        float bi = b_m0[o], gg = g_m0[o], bb = be_m0[o];
        #pragma unroll
        for (int pp = 0; pp < 2; pp++) {
            float v = acc[pp] + bi;
            float s = v, s2 = v * v;
            #pragma unroll
            for (int mk = 1; mk <= 32; mk <<= 1) { s += __shfl_xor(s, mk); s2 += __shfl_xor(s2, mk); }
            float mu = s * (1.f / 64.f);
            float rs = rsqrtf(s2 * (1.f / 64.f) - mu * mu + EPS);
            mmP[pp * 256 + o] = fmaxf(fmaf((v - mu) * rs, gg, bb), 0.f);
        }
    }
    __syncthreads();

    // ---- MLP layer 2 (256->128) + GN(4/32) + ReLU + out_norm GN(16/8) ----
    {
        const int o = tid & 127, pp = tid >> 7;
        const float* wr = w_m1 + o * 256;
        float acc = 0.f;
        for (int c0 = 0; c0 < 256; c0 += 4) {
            float4 w4 = *(const float4*)(wr + c0);
            float4 x4 = *(const float4*)(mmP + pp * 256 + c0);
            acc = fmaf(w4.x, x4.x, acc); acc = fmaf(w4.y, x4.y, acc);
            acc = fmaf(w4.z, x4.z, acc); acc = fmaf(w4.w, x4.w, acc);
        }
        float v = acc + b_m1[o];
        float s = v, s2 = v * v;
        #pragma unroll
        for (int mk = 1; mk <= 16; mk <<= 1) { s += __shfl_xor(s, mk); s2 += __shfl_xor(s2, mk); }
        float mu = s * (1.f / 32.f);
        float rs = rsqrtf(s2 * (1.f / 32.f) - mu * mu + EPS);
        float v2 = fmaxf(fmaf((v - mu) * rs, g_m1[o], be_m1[o]), 0.f);
        float t1 = v2, t2 = v2 * v2;
        #pragma unroll
        for (int mk = 1; mk <= 4; mk <<= 1) { t1 += __shfl_xor(t1, mk); t2 += __shfl_xor(t2, mk); }
        float mu2 = t1 * (1.f / 8.f);
        float rs2 = rsqrtf(t2 * (1.f / 8.f) - mu2 * mu2 + EPS);
        ysP[pp * 128 + o] = fmaf((v2 - mu2) * rs2, g_out[o], b_out[o]);
    }
    __syncthreads();

    // ---- store (float2 across the 2 pixels) ----
    if (tid < 128) {
        float2 y2;
        y2.x = ysP[0 * 128 + tid];
        y2.y = ysP[1 * 128 + tid];
        *(float2*)(out + ((size_t)(b * 128 + tid)) * HWp + pixbase) = y2;
    }
}

extern "C" void kernel_launch(void* const* d_in, const int* in_sizes, int n_in,
                              void* d_out, int out_size, void* d_ws, size_t ws_size,
                              hipStream_t stream) {
    const float* x        = (const float*)d_in[0];
    const int*   bpos     = (const int*)  d_in[1];
    const float* w_in0    = (const float*)d_in[2];
    const float* b_in0    = (const float*)d_in[3];
    const float* g_in0    = (const float*)d_in[4];
    const float* be_in0   = (const float*)d_in[5];
    const float* w_in1    = (const float*)d_in[6];
    const float* b_in1    = (const float*)d_in[7];
    const float* g_in1    = (const float*)d_in[8];
    const float* be_in1   = (const float*)d_in[9];
    const float* g_innorm = (const float*)d_in[10];
    const float* b_innorm = (const float*)d_in[11];
    const float* Qm       = (const float*)d_in[12];
    const float* w_k      = (const float*)d_in[13];
    const float* b_k      = (const float*)d_in[14];
    const float* w_m0     = (const float*)d_in[15];
    const float* b_m0     = (const float*)d_in[16];
    const float* g_m0     = (const float*)d_in[17];
    const float* be_m0    = (const float*)d_in[18];
    const float* w_m1     = (const float*)d_in[19];
    const float* b_m1     = (const float*)d_in[20];
    const float* g_m1     = (const float*)d_in[21];
    const float* be_m1    = (const float*)d_in[22];
    const float* g_out    = (const float*)d_in[23];
    const float* b_out    = (const float*)d_in[24];

    _Float16* w1h  = (_Float16*)d_ws;
    _Float16* w1l  = w1h + 32768;
    _Float16* w2h  = w1l + 32768;
    _Float16* w2l  = w2h + 32768;
    _Float16* qkBh = (_Float16*)((char*)d_ws + 262144);
    _Float16* qkBl = qkBh + 2048;
    float*    qb2G = (float*)((char*)d_ws + 270336);
    float*    peG  = (float*)((char*)d_ws + 270400);

    hipLaunchKernelGGL(ltae_prep, dim3(268), dim3(256), 0, stream,
                       w_in0, w_in1, Qm, w_k, b_k, bpos,
                       w1h, w1l, w2h, w2l, qkBh, qkBl, qb2G, peG);

    hipLaunchKernelGGL(ltae_main, dim3(4608), dim3(256), 0, stream,
                       x,
                       b_in0, g_in0, be_in0,
                       b_in1, g_in1, be_in1,
                       g_innorm, b_innorm,
                       w_m0, b_m0, g_m0, be_m0,
                       w_m1, b_m1, g_m1, be_m1,
                       g_out, b_out,
                       w1h, w1l, w2h, w2l, qkBh, qkBl, qb2G, peG,
                       (float*)d_out);
}

// Round 11
// 433.247 us; speedup vs baseline: 1.4760x; 1.0768x over previous
//
#include <hip/hip_runtime.h>
#include <math.h>

typedef _Float16 f16x8 __attribute__((ext_vector_type(8)));
typedef float f32x4 __attribute__((ext_vector_type(4)));
typedef unsigned short ushort_t;

constexpr int HWp = 2304;
constexpr float EPS = 1e-5f;

// ws layout (bytes): w1h@0, w1l@65536, w2h@131072, w2l@196608 (fp16, 32768 each)
//                    qkBh@262144, qkBl@266240, qb2@270336, peG@270400, o_ws@273664 (4.72 MB)
constexpr size_t OWS_OFF = 273664;

// swizzled ushort index, 256B rows (128 fp16 cols): byte = row*256 + ((c*2)^((row&7)<<4))
__device__ __forceinline__ int sidx(int row, int c) {
    return ((row << 8) + ((c << 1) ^ ((row & 7) << 4))) >> 1;
}

// ---------------- prep: weights -> split fp16 (hi/lo), fold Q+scale, PE table ----------------
__global__ void ltae_prep(const float* __restrict__ w_in0, const float* __restrict__ w_in1,
                          const float* __restrict__ Qm, const float* __restrict__ w_k,
                          const float* __restrict__ b_k, const int* __restrict__ bpos,
                          _Float16* __restrict__ w1h, _Float16* __restrict__ w1l,
                          _Float16* __restrict__ w2h, _Float16* __restrict__ w2l,
                          _Float16* __restrict__ qkBh, _Float16* __restrict__ qkBl,
                          float* __restrict__ qb2G, float* __restrict__ peG) {
    int i = blockIdx.x * 256 + threadIdx.x;
    if (i < 32768) {
        float v = w_in0[i];
        _Float16 h = (_Float16)v;
        w1h[i] = h; w1l[i] = (_Float16)(v - (float)h);
    } else if (i < 65536) {
        int j = i - 32768;
        float v = w_in1[j];
        _Float16 h = (_Float16)v;
        w2h[j] = h; w2l[j] = (_Float16)(v - (float)h);
    } else if (i < 67584) {
        int j = i - 65536; int h = j >> 7, k = j & 127;
        float s = 0.f;
        #pragma unroll
        for (int dk = 0; dk < 4; dk++) s = fmaf(Qm[h * 4 + dk], w_k[(h * 4 + dk) * 128 + k], s);
        s *= 0.5f;
        _Float16 hi = (_Float16)s;
        int ks = k >> 5, lg = (k >> 3) & 3, jj = k & 7;
        int pos = ((ks * 4 + lg) * 16 + h) * 8 + jj;
        qkBh[pos] = hi; qkBl[pos] = (_Float16)(s - (float)hi);
    } else if (i < 67600) {
        int h = i - 67584;
        float s = 0.f;
        #pragma unroll
        for (int dk = 0; dk < 4; dk++) s = fmaf(Qm[h * 4 + dk], b_k[h * 4 + dk], s);
        qb2G[h] = 0.5f * s;
    } else if (i < 68368) {
        int j = i - 67600;
        int bb = j / 192, r = j - bb * 192;
        int t = r >> 3, d = r & 7;
        const float dens[4] = {1.0f, 5.623413251903491f, 31.622776601683793f, 177.82794100389228f};
        float ang = (float)bpos[bb * 24 + t] / dens[d >> 1];
        peG[j] = (d & 1) ? cosf(ang) : sinf(ang);
    }
}

// ---------------- main: 2 pixels per 4-wave block, 3 blocks/CU; ends at o ----------------
__global__ __launch_bounds__(256, 3) void ltae_main(
    const float* __restrict__ x,
    const float* __restrict__ b_in0, const float* __restrict__ g_in0, const float* __restrict__ be_in0,
    const float* __restrict__ b_in1, const float* __restrict__ g_in1, const float* __restrict__ be_in1,
    const float* __restrict__ g_innorm, const float* __restrict__ b_innorm,
    const _Float16* __restrict__ w1h, const _Float16* __restrict__ w1l,
    const _Float16* __restrict__ w2h, const _Float16* __restrict__ w2l,
    const _Float16* __restrict__ qkBh, const _Float16* __restrict__ qkBl,
    const float* __restrict__ qb2G, const float* __restrict__ peG,
    float* __restrict__ o_ws)
{
    __shared__ __align__(16) ushort_t Ah[48 * 128], Al[48 * 128];  // tokens, later xs2 hi/lo
    __shared__ __align__(16) ushort_t Hh[48 * 128], Hl[48 * 128];  // h1 half-tile hi/lo
    __shared__ float peS[24][8];
    __shared__ float muS[2][16], rsS[2][16];
    __shared__ float2 partS[192];     // GN cross-wave partials

    float* scP = (float*)Hh;          // [2][16][24] overlays H after GEMMs

    const int tid = threadIdx.x;
    const int bid = blockIdx.x;
    const int sb  = (bid & 7) * 576 + (bid >> 3);   // bijective XCD swizzle (4608 = 8*576)
    const int b   = sb / 1152;
    const int pixbase = (sb - b * 1152) * 2;
    const int w  = tid >> 6;
    const int l  = tid & 63;
    const int lr = l & 15;
    const int lg = l >> 4;

    // ---- Phase 0: PE cache + gather tokens -> Ah/Al (split fp16, swizzled) ----
    if (tid < 192) peS[tid >> 3][tid & 7] = peG[b * 192 + tid];
    for (int i = tid; i < 24 * 128; i += 256) {
        int t = i >> 7, c = i & 127;
        const float* gp = x + ((size_t)((b * 24 + t) * 128 + c)) * HWp + pixbase;
        float2 v = *(const float2*)gp;
        _Float16 h0 = (_Float16)v.x;
        _Float16 h1 = (_Float16)v.y;
        int i0 = sidx(t, c), i1 = sidx(24 + t, c);
        Ah[i0] = __builtin_bit_cast(ushort_t, h0);
        Al[i0] = __builtin_bit_cast(ushort_t, (_Float16)(v.x - (float)h0));
        Ah[i1] = __builtin_bit_cast(ushort_t, h1);
        Al[i1] = __builtin_bit_cast(ushort_t, (_Float16)(v.y - (float)h1));
    }
    __syncthreads();

    // ---- GEMM1 (two N-halves) + GEMM2 (partial-accumulate over K-halves) ----
    f32x4 acc2[3][2];
    #pragma unroll
    for (int m = 0; m < 3; m++)
        #pragma unroll
        for (int nt = 0; nt < 2; nt++) acc2[m][nt] = f32x4{0.f, 0.f, 0.f, 0.f};

    #pragma unroll 1
    for (int half = 0; half < 2; half++) {
        f16x8 bh[2][4], bl[2][4];
        float gg[2], bb[2], bi[2];
        #pragma unroll
        for (int nt = 0; nt < 2; nt++) {
            int n = half * 128 + w * 32 + nt * 16 + lr;
            #pragma unroll
            for (int ks = 0; ks < 4; ks++) {
                bh[nt][ks] = *(const f16x8*)(w1h + n * 128 + ks * 32 + lg * 8);
                bl[nt][ks] = *(const f16x8*)(w1l + n * 128 + ks * 32 + lg * 8);
            }
            gg[nt] = g_in0[n]; bb[nt] = be_in0[n]; bi[nt] = b_in0[n];
        }
        f32x4 acc[3][2];
        #pragma unroll
        for (int m = 0; m < 3; m++)
            #pragma unroll
            for (int nt = 0; nt < 2; nt++) acc[m][nt] = f32x4{0.f, 0.f, 0.f, 0.f};
        #pragma unroll
        for (int m = 0; m < 3; m++) {
            #pragma unroll
            for (int ks = 0; ks < 4; ks++) {
                f16x8 ah = *(const f16x8*)&Ah[sidx(m * 16 + lr, ks * 32 + lg * 8)];
                f16x8 al = *(const f16x8*)&Al[sidx(m * 16 + lr, ks * 32 + lg * 8)];
                #pragma unroll
                for (int nt = 0; nt < 2; nt++) {
                    acc[m][nt] = __builtin_amdgcn_mfma_f32_16x16x32_f16(ah, bl[nt][ks], acc[m][nt], 0, 0, 0);
                    acc[m][nt] = __builtin_amdgcn_mfma_f32_16x16x32_f16(al, bh[nt][ks], acc[m][nt], 0, 0, 0);
                    acc[m][nt] = __builtin_amdgcn_mfma_f32_16x16x32_f16(ah, bh[nt][ks], acc[m][nt], 0, 0, 0);
                }
            }
        }
        float ps[3][4], ps2[3][4];
        #pragma unroll
        for (int m = 0; m < 3; m++) {
            #pragma unroll
            for (int r = 0; r < 4; r++) {
                float v0 = acc[m][0][r] + bi[0], v1 = acc[m][1][r] + bi[1];
                float s = v0 + v1, s2 = v0 * v0 + v1 * v1;
                #pragma unroll
                for (int mk = 1; mk <= 8; mk <<= 1) { s += __shfl_xor(s, mk); s2 += __shfl_xor(s2, mk); }
                ps[m][r] = s; ps2[m][r] = s2;
            }
        }
        if (lr == 0) {
            #pragma unroll
            for (int m = 0; m < 3; m++)
                #pragma unroll
                for (int r = 0; r < 4; r++)
                    partS[w * 48 + m * 16 + lg * 4 + r] = make_float2(ps[m][r], ps2[m][r]);
        }
        __syncthreads();
        #pragma unroll
        for (int m = 0; m < 3; m++) {
            #pragma unroll
            for (int r = 0; r < 4; r++) {
                float2 q = partS[(w ^ 1) * 48 + m * 16 + lg * 4 + r];
                float st = ps[m][r] + q.x, s2t = ps2[m][r] + q.y;
                float mu = st * (1.f / 64.f);
                float rs = rsqrtf(s2t * (1.f / 64.f) - mu * mu + EPS);
                int row = m * 16 + lg * 4 + r;
                #pragma unroll
                for (int nt = 0; nt < 2; nt++) {
                    float v = acc[m][nt][r] + bi[nt];
                    float hv = fmaxf(fmaf((v - mu) * rs, gg[nt], bb[nt]), 0.f);
                    _Float16 h16 = (_Float16)hv;
                    int ii = sidx(row, w * 32 + nt * 16 + lr);
                    Hh[ii] = __builtin_bit_cast(ushort_t, h16);
                    Hl[ii] = __builtin_bit_cast(ushort_t, (_Float16)(hv - (float)h16));
                }
            }
        }
        __syncthreads();

        f16x8 b2h[2][4], b2l[2][4];
        #pragma unroll
        for (int nt = 0; nt < 2; nt++) {
            int n = w * 32 + nt * 16 + lr;
            #pragma unroll
            for (int ks = 0; ks < 4; ks++) {
                b2h[nt][ks] = *(const f16x8*)(w2h + n * 256 + half * 128 + ks * 32 + lg * 8);
                b2l[nt][ks] = *(const f16x8*)(w2l + n * 256 + half * 128 + ks * 32 + lg * 8);
            }
        }
        #pragma unroll
        for (int m = 0; m < 3; m++) {
            #pragma unroll
            for (int ks = 0; ks < 4; ks++) {
                f16x8 ah = *(const f16x8*)&Hh[sidx(m * 16 + lr, ks * 32 + lg * 8)];
                f16x8 al = *(const f16x8*)&Hl[sidx(m * 16 + lr, ks * 32 + lg * 8)];
                #pragma unroll
                for (int nt = 0; nt < 2; nt++) {
                    acc2[m][nt] = __builtin_amdgcn_mfma_f32_16x16x32_f16(ah, b2l[nt][ks], acc2[m][nt], 0, 0, 0);
                    acc2[m][nt] = __builtin_amdgcn_mfma_f32_16x16x32_f16(al, b2h[nt][ks], acc2[m][nt], 0, 0, 0);
                    acc2[m][nt] = __builtin_amdgcn_mfma_f32_16x16x32_f16(ah, b2h[nt][ks], acc2[m][nt], 0, 0, 0);
                }
            }
        }
        __syncthreads();
    }

    // ---- GN2 (wave-local, 32-ch groups) + ReLU -> xs2 hi/lo (A region) ----
    {
        float gg2[2], bb2[2], bi2[2];
        #pragma unroll
        for (int nt = 0; nt < 2; nt++) {
            int n = w * 32 + nt * 16 + lr;
            gg2[nt] = g_in1[n]; bb2[nt] = be_in1[n]; bi2[nt] = b_in1[n];
        }
        #pragma unroll
        for (int m = 0; m < 3; m++) {
            #pragma unroll
            for (int r = 0; r < 4; r++) {
                float v0 = acc2[m][0][r] + bi2[0], v1 = acc2[m][1][r] + bi2[1];
                float s = v0 + v1, s2 = v0 * v0 + v1 * v1;
                #pragma unroll
                for (int mk = 1; mk <= 8; mk <<= 1) { s += __shfl_xor(s, mk); s2 += __shfl_xor(s2, mk); }
                float mu = s * (1.f / 32.f);
                float rs = rsqrtf(s2 * (1.f / 32.f) - mu * mu + EPS);
                int row = m * 16 + lg * 4 + r;
                float h0 = fmaxf(fmaf((v0 - mu) * rs, gg2[0], bb2[0]), 0.f);
                float h1v = fmaxf(fmaf((v1 - mu) * rs, gg2[1], bb2[1]), 0.f);
                _Float16 p0 = (_Float16)h0, p1 = (_Float16)h1v;
                int i0 = sidx(row, w * 32 + lr), i1 = sidx(row, w * 32 + 16 + lr);
                Ah[i0] = __builtin_bit_cast(ushort_t, p0);
                Al[i0] = __builtin_bit_cast(ushort_t, (_Float16)(h0 - (float)p0));
                Ah[i1] = __builtin_bit_cast(ushort_t, p1);
                Al[i1] = __builtin_bit_cast(ushort_t, (_Float16)(h1v - (float)p1));
            }
        }
    }
    __syncthreads();

    // ---- Phase 3: in_norm GN(16 over C,T) stats ----
    {
        const int p = w >> 1, hw = w & 1;
        int g = hw * 8 + (l >> 3), j = l & 7;
        float s = 0.f, s2 = 0.f;
        #pragma unroll
        for (int k = 0; k < 24; k++) {
            int e = j + 8 * k;
            int t = e >> 3, co = e & 7;
            int ii = sidx(p * 24 + t, g * 8 + co);
            float v = (float)__builtin_bit_cast(_Float16, Ah[ii]) +
                      (float)__builtin_bit_cast(_Float16, Al[ii]);
            s += v; s2 += v * v;
        }
        s += __shfl_xor(s, 1);  s += __shfl_xor(s, 2);  s += __shfl_xor(s, 4);
        s2 += __shfl_xor(s2, 1); s2 += __shfl_xor(s2, 2); s2 += __shfl_xor(s2, 4);
        if (j == 0) {
            float mu = s * (1.f / 192.f);
            muS[p][g] = mu;
            rsS[p][g] = rsqrtf(s2 * (1.f / 192.f) - mu * mu + EPS);
        }
    }
    __syncthreads();
    for (int i = tid; i < 48 * 128; i += 256) {
        int row = i >> 7, c = i & 127;
        int p = row >= 24 ? 1 : 0;
        int t = row - p * 24;
        int ii = sidx(row, c);
        float v = (float)__builtin_bit_cast(_Float16, Ah[ii]) +
                  (float)__builtin_bit_cast(_Float16, Al[ii]);
        v = (v - muS[p][c >> 3]) * rsS[p][c >> 3] * g_innorm[c] + b_innorm[c] + peS[t][c & 7];
        _Float16 h16 = (_Float16)v;
        Ah[ii] = __builtin_bit_cast(ushort_t, h16);
        Al[ii] = __builtin_bit_cast(ushort_t, (_Float16)(v - (float)h16));
    }
    __syncthreads();

    // ---- Phase 4: scores via split-fp16 MFMA (waves 0..2) ----
    if (w < 3) {
        const int m = w;
        f16x8 qh[4], ql[4];
        #pragma unroll
        for (int ks = 0; ks < 4; ks++) {
            qh[ks] = *(const f16x8*)(qkBh + ((ks * 4 + lg) * 16 + lr) * 8);
            ql[ks] = *(const f16x8*)(qkBl + ((ks * 4 + lg) * 16 + lr) * 8);
        }
        f32x4 sacc = f32x4{0.f, 0.f, 0.f, 0.f};
        #pragma unroll
        for (int ks = 0; ks < 4; ks++) {
            f16x8 ah = *(const f16x8*)&Ah[sidx(m * 16 + lr, ks * 32 + lg * 8)];
            f16x8 al = *(const f16x8*)&Al[sidx(m * 16 + lr, ks * 32 + lg * 8)];
            sacc = __builtin_amdgcn_mfma_f32_16x16x32_f16(ah, ql[ks], sacc, 0, 0, 0);
            sacc = __builtin_amdgcn_mfma_f32_16x16x32_f16(al, qh[ks], sacc, 0, 0, 0);
            sacc = __builtin_amdgcn_mfma_f32_16x16x32_f16(ah, qh[ks], sacc, 0, 0, 0);
        }
        float qb = qb2G[lr];
        #pragma unroll
        for (int r = 0; r < 4; r++) {
            int row = m * 16 + lg * 4 + r;
            int p = row >= 24 ? 1 : 0;
            int t = row - p * 24;
            scP[(p * 16 + lr) * 24 + t] = sacc[r] + qb;
        }
    }
    __syncthreads();

    // ---- softmax: wave w -> pixel w>>1, heads (w&1)*8 + l>>3 ----
    {
        const int p = w >> 1;
        int h = (w & 1) * 8 + (l >> 3), j = l & 7;
        float* sp = scP + (p * 16 + h) * 24;
        float mx = -1e30f;
        #pragma unroll
        for (int k = 0; k < 3; k++) mx = fmaxf(mx, sp[j + 8 * k]);
        mx = fmaxf(mx, __shfl_xor(mx, 1));
        mx = fmaxf(mx, __shfl_xor(mx, 2));
        mx = fmaxf(mx, __shfl_xor(mx, 4));
        float ev[3], sum = 0.f;
        #pragma unroll
        for (int k = 0; k < 3; k++) { ev[k] = __expf(sp[j + 8 * k] - mx); sum += ev[k]; }
        sum += __shfl_xor(sum, 1);
        sum += __shfl_xor(sum, 2);
        sum += __shfl_xor(sum, 4);
        float inv = 1.f / sum;
        #pragma unroll
        for (int k = 0; k < 3; k++) sp[j + 8 * k] = ev[k] * inv;
    }

    // ---- Phase 5: o = a . v -> global o_ws; kernel A ends here ----
    {
        const int p = w >> 1;
        int ch = (w & 1) * 64 + l;
        int h = ch >> 3;
        const float* sp = scP + (p * 16 + h) * 24;
        float s = 0.f;
        #pragma unroll
        for (int t = 0; t < 24; t++) {
            int ii = sidx(p * 24 + t, ch);
            float v = (float)__builtin_bit_cast(_Float16, Ah[ii]) +
                      (float)__builtin_bit_cast(_Float16, Al[ii]);
            s = fmaf(sp[t], v, s);
        }
        o_ws[((size_t)(b * 2304 + pixbase + p)) * 128 + ch] = s;
    }
}

// ---------------- mlp: output MLP + norms, 8 pixels per 256-thread block ----------------
__global__ __launch_bounds__(256) void ltae_mlp(
    const float* __restrict__ o_ws,
    const float* __restrict__ w_m0, const float* __restrict__ b_m0,
    const float* __restrict__ g_m0, const float* __restrict__ be_m0,
    const float* __restrict__ w_m1, const float* __restrict__ b_m1,
    const float* __restrict__ g_m1, const float* __restrict__ be_m1,
    const float* __restrict__ g_out, const float* __restrict__ b_out,
    float* __restrict__ out)
{
    __shared__ float ovP[8 * 128];    // later reused as ysP
    __shared__ float mmP[8 * 256];
    float* ysP = ovP;

    const int tid = threadIdx.x;
    const int bid = blockIdx.x;       // 1152 = 4 b * 288
    const int b = bid / 288;
    const int pix8 = (bid - b * 288) * 8;

    // load o for 8 pixels (coalesced)
    #pragma unroll
    for (int k = 0; k < 4; k++) {
        int i = tid + (k << 8);       // 0..1023
        ovP[i] = o_ws[((size_t)(b * 2304 + pix8)) * 128 + i];
    }
    __syncthreads();

    // MLP layer 1 (128->256) + GN(4/64) + ReLU, 8 pixels
    {
        const int o = tid;
        const float* wr = w_m0 + o * 128;
        float acc[8];
        #pragma unroll
        for (int pp = 0; pp < 8; pp++) acc[pp] = 0.f;
        for (int c0 = 0; c0 < 128; c0 += 4) {
            float4 w4 = *(const float4*)(wr + c0);
            #pragma unroll
            for (int pp = 0; pp < 8; pp++) {
                float4 x4 = *(const float4*)(ovP + pp * 128 + c0);
                acc[pp] = fmaf(w4.x, x4.x, acc[pp]); acc[pp] = fmaf(w4.y, x4.y, acc[pp]);
                acc[pp] = fmaf(w4.z, x4.z, acc[pp]); acc[pp] = fmaf(w4.w, x4.w, acc[pp]);
            }
        }
        float bi = b_m0[o], gg = g_m0[o], bb = be_m0[o];
        #pragma unroll
        for (int pp = 0; pp < 8; pp++) {
            float v = acc[pp] + bi;
            float s = v, s2 = v * v;
            #pragma unroll
            for (int mk = 1; mk <= 32; mk <<= 1) { s += __shfl_xor(s, mk); s2 += __shfl_xor(s2, mk); }
            float mu = s * (1.f / 64.f);
            float rs = rsqrtf(s2 * (1.f / 64.f) - mu * mu + EPS);
            mmP[pp * 256 + o] = fmaxf(fmaf((v - mu) * rs, gg, bb), 0.f);
        }
    }
    __syncthreads();

    // MLP layer 2 (256->128) + GN(4/32) + ReLU + out_norm GN(16/8)
    {
        const int o = tid & 127, hw = tid >> 7;
        const float* wr = w_m1 + o * 256;
        float gm1 = g_m1[o], bem1 = be_m1[o], bm1 = b_m1[o];
        float go = g_out[o], bo = b_out[o];
        #pragma unroll
        for (int q = 0; q < 4; q++) {
            const int pp = hw * 4 + q;
            float acc = 0.f;
            for (int c0 = 0; c0 < 256; c0 += 4) {
                float4 w4 = *(const float4*)(wr + c0);
                float4 x4 = *(const float4*)(mmP + pp * 256 + c0);
                acc = fmaf(w4.x, x4.x, acc); acc = fmaf(w4.y, x4.y, acc);
                acc = fmaf(w4.z, x4.z, acc); acc = fmaf(w4.w, x4.w, acc);
            }
            float v = acc + bm1;
            float s = v, s2 = v * v;
            #pragma unroll
            for (int mk = 1; mk <= 16; mk <<= 1) { s += __shfl_xor(s, mk); s2 += __shfl_xor(s2, mk); }
            float mu = s * (1.f / 32.f);
            float rs = rsqrtf(s2 * (1.f / 32.f) - mu * mu + EPS);
            float v2 = fmaxf(fmaf((v - mu) * rs, gm1, bem1), 0.f);
            float t1 = v2, t2 = v2 * v2;
            #pragma unroll
            for (int mk = 1; mk <= 4; mk <<= 1) { t1 += __shfl_xor(t1, mk); t2 += __shfl_xor(t2, mk); }
            float mu2 = t1 * (1.f / 8.f);
            float rs2 = rsqrtf(t2 * (1.f / 8.f) - mu2 * mu2 + EPS);
            ysP[pp * 128 + o] = fmaf((v2 - mu2) * rs2, go, bo);
        }
    }
    __syncthreads();

    // store: float4 across 4 consecutive pixels
    {
        const int o = tid & 127, q4 = (tid >> 7) * 4;
        float4 y4;
        y4.x = ysP[(q4 + 0) * 128 + o];
        y4.y = ysP[(q4 + 1) * 128 + o];
        y4.z = ysP[(q4 + 2) * 128 + o];
        y4.w = ysP[(q4 + 3) * 128 + o];
        *(float4*)(out + ((size_t)(b * 128 + o)) * HWp + pix8 + q4) = y4;
    }
}

extern "C" void kernel_launch(void* const* d_in, const int* in_sizes, int n_in,
                              void* d_out, int out_size, void* d_ws, size_t ws_size,
                              hipStream_t stream) {
    const float* x        = (const float*)d_in[0];
    const int*   bpos     = (const int*)  d_in[1];
    const float* w_in0    = (const float*)d_in[2];
    const float* b_in0    = (const float*)d_in[3];
    const float* g_in0    = (const float*)d_in[4];
    const float* be_in0   = (const float*)d_in[5];
    const float* w_in1    = (const float*)d_in[6];
    const float* b_in1    = (const float*)d_in[7];
    const float* g_in1    = (const float*)d_in[8];
    const float* be_in1   = (const float*)d_in[9];
    const float* g_innorm = (const float*)d_in[10];
    const float* b_innorm = (const float*)d_in[11];
    const float* Qm       = (const float*)d_in[12];
    const float* w_k      = (const float*)d_in[13];
    const float* b_k      = (const float*)d_in[14];
    const float* w_m0     = (const float*)d_in[15];
    const float* b_m0     = (const float*)d_in[16];
    const float* g_m0     = (const float*)d_in[17];
    const float* be_m0    = (const float*)d_in[18];
    const float* w_m1     = (const float*)d_in[19];
    const float* b_m1     = (const float*)d_in[20];
    const float* g_m1     = (const float*)d_in[21];
    const float* be_m1    = (const float*)d_in[22];
    const float* g_out    = (const float*)d_in[23];
    const float* b_out    = (const float*)d_in[24];

    _Float16* w1h  = (_Float16*)d_ws;
    _Float16* w1l  = w1h + 32768;
    _Float16* w2h  = w1l + 32768;
    _Float16* w2l  = w2h + 32768;
    _Float16* qkBh = (_Float16*)((char*)d_ws + 262144);
    _Float16* qkBl = qkBh + 2048;
    float*    qb2G = (float*)((char*)d_ws + 270336);
    float*    peG  = (float*)((char*)d_ws + 270400);
    float*    o_ws = (float*)((char*)d_ws + OWS_OFF);

    hipLaunchKernelGGL(ltae_prep, dim3(268), dim3(256), 0, stream,
                       w_in0, w_in1, Qm, w_k, b_k, bpos,
                       w1h, w1l, w2h, w2l, qkBh, qkBl, qb2G, peG);

    hipLaunchKernelGGL(ltae_main, dim3(4608), dim3(256), 0, stream,
                       x,
                       b_in0, g_in0, be_in0,
                       b_in1, g_in1, be_in1,
                       g_innorm, b_innorm,
                       w1h, w1l, w2h, w2l, qkBh, qkBl, qb2G, peG,
                       o_ws);

    hipLaunchKernelGGL(ltae_mlp, dim3(1152), dim3(256), 0, stream,
                       o_ws,
                       w_m0, b_m0, g_m0, be_m0,
                       w_m1, b_m1, g_m1, be_m1,
                       g_out, b_out,
                       (float*)d_out);
}